// Round 1
// baseline (2485.048 us; speedup 1.0000x reference)
//
#include <hip/hip_runtime.h>
#include <hip/hip_bf16.h>

// ---------------- problem constants ----------------
#define HID 128
static const int N_NODES = 50000;
static const int N_EDGES = 20000;
static const int M_COPIES = 400000;
static const int L_EDGES = 800000;
static const int NBATCH = 32;
static const int NCLS = 10;
#define INV_STD 0.9999950000374997f   // 1/sqrt(1+1e-5)
#define IDX_CAP 384                   // per-block item cap (avg 128; global fallback)

typedef __attribute__((ext_vector_type(4))) float f32x4;
typedef __attribute__((ext_vector_type(8))) short short8;      // 8 bf16 lanes
typedef __attribute__((ext_vector_type(8))) unsigned short ushort8;
typedef __attribute__((ext_vector_type(4))) unsigned short u16x4;  // 'ushort4' collides with HIP header

__device__ __forceinline__ float bf2f(unsigned short u) {
    union { unsigned u; float f; } v; v.u = ((unsigned)u) << 16; return v.f;
}
__device__ __forceinline__ unsigned short f2bf(float f) {
    union { float f; unsigned u; } v; v.f = f;
    unsigned r = v.u + 0x7FFFu + ((v.u >> 16) & 1u);   // RNE
    return (unsigned short)(r >> 16);
}
__device__ __forceinline__ void gatomic_add(float* p, float v) {
    unsafeAtomicAdd(p, v);
}

// Swizzled Xs addressing: logical [chunk c][row r][8 bf16], 16 B per (c,r).
// byte = (c*1024 + r*16) ^ ((c&7)<<4) -> gather writes (c fast-varying across
// lanes) land on 8 distinct 16B slots instead of 1 (was a 16-way conflict).
__device__ __forceinline__ unsigned short* xs_addr(unsigned short* Xs, int c, int r) {
    int byte = ((c * 64 + r) * 16) ^ ((c & 7) << 4);
    return (unsigned short*)((char*)Xs + byte);
}

// ---------------- weight prep: Wt[mat][n][k] = bf16(W[mat][k][n]) ----------------
__global__ __launch_bounds__(256) void prep_w(const float* __restrict__ We,
                                              const float* __restrict__ Wg,
                                              unsigned short* __restrict__ Wt) {
    int t = blockIdx.x * 256 + threadIdx.x;       // 17*16384
    if (t >= 17 * 16384) return;
    int mat = t >> 14, rem = t & 16383;
    int n = rem >> 7, k = rem & 127;
    const float* src = (mat == 0) ? We : (Wg + (size_t)(mat - 1) * 16384);
    Wt[t] = f2bf(src[k * 128 + n]);
}

// ---------------- CSR build ----------------
__global__ __launch_bounds__(256) void hist_k(const int* __restrict__ idx, int n,
                                              int* __restrict__ cnt) {
    int t = blockIdx.x * 256 + threadIdx.x;
    if (t < n) atomicAdd(&cnt[idx[t]], 1);
}

__global__ __launch_bounds__(256) void scan1_k(int* __restrict__ a, int n,
                                               int* __restrict__ part) {
    __shared__ int s[256];
    int i = blockIdx.x * 256 + threadIdx.x;
    int v = (i < n) ? a[i] : 0;
    s[threadIdx.x] = v;
    __syncthreads();
#pragma unroll
    for (int d = 1; d < 256; d <<= 1) {
        int t = (threadIdx.x >= d) ? s[threadIdx.x - d] : 0;
        __syncthreads();
        s[threadIdx.x] += t;
        __syncthreads();
    }
    if (i < n) a[i] = s[threadIdx.x] - v;
    if (threadIdx.x == 255) part[blockIdx.x] = s[255];
}

__global__ __launch_bounds__(256) void scan2_k(int* __restrict__ part, int nb) {
    __shared__ int s[256];
    __shared__ int carry;
    if (threadIdx.x == 0) carry = 0;
    __syncthreads();
    for (int base = 0; base < nb; base += 256) {
        int i = base + threadIdx.x;
        int v = (i < nb) ? part[i] : 0;
        s[threadIdx.x] = v;
        __syncthreads();
#pragma unroll
        for (int d = 1; d < 256; d <<= 1) {
            int t = (threadIdx.x >= d) ? s[threadIdx.x - d] : 0;
            __syncthreads();
            s[threadIdx.x] += t;
            __syncthreads();
        }
        if (i < nb) part[i] = carry + s[threadIdx.x] - v;
        __syncthreads();
        if (threadIdx.x == 0) carry += s[255];
        __syncthreads();
    }
}

__global__ __launch_bounds__(256) void scan3_k(int* __restrict__ a, int n,
                                               const int* __restrict__ part) {
    int i = blockIdx.x * 256 + threadIdx.x;
    if (i < n) a[i] += part[blockIdx.x];
}

__global__ __launch_bounds__(256) void fill_edge_k(
    const int* __restrict__ src, const int* __restrict__ dst,
    const int* __restrict__ remap, int n, int* __restrict__ off,
    int* __restrict__ srcs, int* __restrict__ comps) {
    int e = blockIdx.x * 256 + threadIdx.x;
    if (e >= n) return;
    int d = dst[e];
    int pos = atomicAdd(&off[d], 1);
    int s = src[e];
    srcs[pos] = s;
    comps[pos] = remap[s];
}

__global__ __launch_bounds__(256) void fill_pool_k(
    const int* __restrict__ seg, int n, int* __restrict__ off,
    int* __restrict__ items) {
    int m = blockIdx.x * 256 + threadIdx.x;
    if (m >= n) return;
    int pos = atomicAdd(&off[seg[m]], 1);
    items[pos] = m;
}

// ---------------- pool segment sum: wave-per-segment, 4 rows in flight ----------------
// lane (g=lane&15, sub=lane>>4): accumulates chunk g of items pos+sub; shuffle-reduce over sub.
__global__ __launch_bounds__(256) void segsum_pool(
    const unsigned short* __restrict__ tbl, const int* __restrict__ off,
    const int* __restrict__ items, unsigned short* __restrict__ out, int nseg)
{
    int wave = threadIdx.x >> 6, lane = threadIdx.x & 63;
    int seg = blockIdx.x * 4 + wave;
    if (seg >= nseg) return;
    int start = (seg == 0) ? 0 : off[seg - 1];
    int end = off[seg];
    int g = lane & 15, sub = lane >> 4;
    float a[8] = {0.f, 0.f, 0.f, 0.f, 0.f, 0.f, 0.f, 0.f};
    for (int p = start + sub; p < end; p += 4) {
        int r = items[p];                          // broadcast across the 16 g-lanes
        ushort8 v = *(const ushort8*)(tbl + (size_t)r * 128 + g * 8);
#pragma unroll
        for (int j = 0; j < 8; ++j) a[j] += bf2f(v[j]);
    }
#pragma unroll
    for (int j = 0; j < 8; ++j) {
        a[j] += __shfl_xor(a[j], 16, 64);
        a[j] += __shfl_xor(a[j], 32, 64);
    }
    if (sub == 0) {
        ushort8 ov;
#pragma unroll
        for (int j = 0; j < 8; ++j) ov[j] = f2bf(fmaxf(a[j], 0.f));
        *(ushort8*)(out + (size_t)seg * 128 + g * 8) = ov;
    }
}

// ---------------- fused GIN conv: 256 thr / 64 rows ----------------
// gather-segsum + linear1+ReLU + linear2+BN(+ReLU).
// W fragments are read DIRECTLY from global (W1t/W2t are 32 KB each, identical
// across all 6250 blocks -> L1/L2-resident). This removes the Ws LDS buffer,
// its 16-way-conflicting staging writes, and all 32 restaging barriers.
// After the single post-gather barrier, every wave touches only its own 16 Xs
// rows (X-frag reads, H writes, H-frag reads) -> no further __syncthreads.
template<bool CONV0>
__global__ __launch_bounds__(256, 6) void fused_conv(
    const unsigned short* __restrict__ tbl,
    const int* __restrict__ self_idx,
    const int* __restrict__ off, const int* __restrict__ items,
    const float* __restrict__ eps_ptr,
    const unsigned short* __restrict__ W1t, const float* __restrict__ b1,
    const unsigned short* __restrict__ W2t, const float* __restrict__ b2,
    const float* __restrict__ gam, const float* __restrict__ bet,
    unsigned short* __restrict__ out)
{
    __shared__ __align__(16) unsigned short Xs[16 * 64 * 8];  // 16 KB, swizzled
    __shared__ int sIdx[IDX_CAP];                             // 1.5 KB
    __shared__ int meta[192];                                 // 0.75 KB
    const int tid = threadIdx.x;
    const int row0 = blockIdx.x * 64;

    const int bstart = (row0 == 0) ? 0 : off[row0 - 1];
    const int cnt = off[row0 + 63] - bstart;
    const bool useLds = (cnt <= IDX_CAP);

    if (tid < 64) {
        int gr = row0 + tid;
        meta[tid]       = (gr == 0) ? 0 : off[gr - 1];
        meta[64 + tid]  = off[gr];
        meta[128 + tid] = CONV0 ? self_idx[gr] : gr;
    }
    if (useLds)
        for (int i = tid; i < cnt; i += 256) sIdx[i] = items[bstart + i];
    __syncthreads();

    // ---- gather: thread (rb,g) walks rows rb+16i; idx from LDS, 2-wide loads ----
    const float e = 1.0f + eps_ptr[0];
    const int g = tid & 15;
    const int rb = tid >> 4;        // 0..15
#pragma unroll
    for (int i = 0; i < 4; ++i) {
        int r = rb + 16 * i;
        int start = meta[r], end = meta[64 + r], self = meta[128 + r];
        float a[8];
        ushort8 u = *(const ushort8*)(tbl + (size_t)self * 128 + g * 8);
#pragma unroll
        for (int j = 0; j < 8; ++j) a[j] = e * bf2f(u[j]);
        if (useLds) {
            int pos = start - bstart, pe = end - bstart;
            for (; pos + 2 <= pe; pos += 2) {
                int i0 = sIdx[pos], i1 = sIdx[pos + 1];
                ushort8 v0 = *(const ushort8*)(tbl + (size_t)i0 * 128 + g * 8);
                ushort8 v1 = *(const ushort8*)(tbl + (size_t)i1 * 128 + g * 8);
#pragma unroll
                for (int j = 0; j < 8; ++j) a[j] += bf2f(v0[j]) + bf2f(v1[j]);
            }
            if (pos < pe) {
                int i0 = sIdx[pos];
                ushort8 v0 = *(const ushort8*)(tbl + (size_t)i0 * 128 + g * 8);
#pragma unroll
                for (int j = 0; j < 8; ++j) a[j] += bf2f(v0[j]);
            }
        } else {
            for (int pos = start; pos < end; ++pos) {
                int rr = items[pos];
                ushort8 v = *(const ushort8*)(tbl + (size_t)rr * 128 + g * 8);
#pragma unroll
                for (int j = 0; j < 8; ++j) a[j] += bf2f(v[j]);
            }
        }
        ushort8 xv;
#pragma unroll
        for (int j = 0; j < 8; ++j) xv[j] = f2bf(a[j]);
        *(ushort8*)xs_addr(Xs, g, r) = xv;
    }
    __syncthreads();   // the ONLY cross-wave hazard: gather writes span all waves' rows

    const int lane = tid & 63;
    const int ln = lane & 15, quad = lane >> 4;
    const int row = (tid >> 6) * 16 + ln;   // wave-private X/H row (4 waves x 16 = 64)

    // hoist X fragments (wave reads only its own rows)
    short8 xb[4];
#pragma unroll
    for (int kc = 0; kc < 4; ++kc)
        xb[kc] = *(const short8*)xs_addr(Xs, kc * 4 + quad, row);

    f32x4 acc[8];
#pragma unroll
    for (int t = 0; t < 8; ++t) acc[t] = (f32x4){0.f, 0.f, 0.f, 0.f};

    // ---- MFMA 1: W frags from global. wa(t,kc) = W1t[(t*16+ln)*128 + (kc*4+quad)*8]
    // kc-outer / t-inner: 8 consecutive MFMAs hit distinct accumulators (no RAW chain)
    {
        const unsigned short* w1p = W1t + ln * 128 + quad * 8;
#pragma unroll
        for (int kc = 0; kc < 4; ++kc) {
#pragma unroll
            for (int t = 0; t < 8; ++t) {
                short8 wa = *(const short8*)(w1p + t * 2048 + kc * 32);
                acc[t] = __builtin_amdgcn_mfma_f32_16x16x32_bf16(wa, xb[kc], acc[t], 0, 0, 0);
            }
        }
    }

    // h = relu(acc + b1) -> Xs (own rows only; same-wave LDS ordering suffices)
    {
        const int j0 = (quad & 1) * 4;
#pragma unroll
        for (int t = 0; t < 8; ++t) {
            int p0 = t * 16 + quad * 4;
            f32x4 bv = *(const f32x4*)(b1 + p0);
            u16x4 hp;
#pragma unroll
            for (int i = 0; i < 4; ++i) hp[i] = f2bf(fmaxf(acc[t][i] + bv[i], 0.f));
            *(u16x4*)((char*)xs_addr(Xs, p0 >> 3, row) + j0 * 2) = hp;
        }
    }

    // hoist H fragments (own rows, written by own wave's lanes)
    short8 hb[4];
#pragma unroll
    for (int kc = 0; kc < 4; ++kc)
        hb[kc] = *(const short8*)xs_addr(Xs, kc * 4 + quad, row);

#pragma unroll
    for (int t = 0; t < 8; ++t) acc[t] = (f32x4){0.f, 0.f, 0.f, 0.f};

    // ---- MFMA 2 ----
    {
        const unsigned short* w2p = W2t + ln * 128 + quad * 8;
#pragma unroll
        for (int kc = 0; kc < 4; ++kc) {
#pragma unroll
            for (int t = 0; t < 8; ++t) {
                short8 wa = *(const short8*)(w2p + t * 2048 + kc * 32);
                acc[t] = __builtin_amdgcn_mfma_f32_16x16x32_bf16(wa, hb[kc], acc[t], 0, 0, 0);
            }
        }
    }

    // epilogue: lane holds out[row0+row][n0..n0+3] -> 8B stores
    const int m = row0 + row;
#pragma unroll
    for (int t = 0; t < 8; ++t) {
        int n0 = t * 16 + quad * 4;
        f32x4 bv = *(const f32x4*)(b2 + n0);
        f32x4 gv = *(const f32x4*)(gam + n0);
        f32x4 tv = *(const f32x4*)(bet + n0);
        u16x4 op;
#pragma unroll
        for (int i = 0; i < 4; ++i) {
            float h = acc[t][i] + bv[i];
            h = gv[i] * h * INV_STD + tv[i];
            if (CONV0) h = fmaxf(h, 0.f);
            op[i] = f2bf(h);
        }
        *(u16x4*)(out + (size_t)m * 128 + n0) = op;
    }
}

// ---------------- embedding GEMM (f32 in): out = in @ W + b ----------------
__global__ __launch_bounds__(256) void gemm_embed(
    const float* __restrict__ in, const unsigned short* __restrict__ Wt,
    const float* __restrict__ bias, unsigned short* __restrict__ out_bf, int rows)
{
    __shared__ __align__(16) unsigned short Xs[16 * 64 * 8];
    __shared__ __align__(16) unsigned short Ws[16 * 128 * 8];
    int tid = threadIdx.x;
    int row0 = blockIdx.x * 64;
#pragma unroll
    for (int i = 0; i < 8; ++i) {
        int chunk = tid + i * 256;
        int n = chunk >> 4, g = chunk & 15;
        *(short8*)(Ws + (g * 128 + n) * 8) = *(const short8*)(Wt + n * 128 + g * 8);
    }
#pragma unroll
    for (int i = 0; i < 4; ++i) {
        int chunk = tid + i * 256;
        int r = chunk >> 4, g = chunk & 15;
        int gr = row0 + r;
        ushort8 v;
        if (gr < rows) {
            const float* p = in + (size_t)gr * 128 + g * 8;
            f32x4 a0 = *(const f32x4*)p;
            f32x4 a1 = *(const f32x4*)(p + 4);
#pragma unroll
            for (int j = 0; j < 4; ++j) { v[j] = f2bf(a0[j]); v[4 + j] = f2bf(a1[j]); }
        } else {
#pragma unroll
            for (int j = 0; j < 8; ++j) v[j] = 0;
        }
        *(ushort8*)(Xs + (g * 64 + r) * 8) = v;
    }
    __syncthreads();
    int wave = tid >> 6, lane = tid & 63;
    int m0 = wave * 16;
    int ln = lane & 15, quad = lane >> 4;
    f32x4 acc[8];
#pragma unroll
    for (int t = 0; t < 8; ++t) acc[t] = (f32x4){0.f, 0.f, 0.f, 0.f};
#pragma unroll
    for (int kc = 0; kc < 4; ++kc) {
        int g = kc * 4 + quad;
        short8 a = *(const short8*)(Xs + (g * 64 + m0 + ln) * 8);
#pragma unroll
        for (int t = 0; t < 8; ++t) {
            short8 b = *(const short8*)(Ws + (g * 128 + t * 16 + ln) * 8);
            acc[t] = __builtin_amdgcn_mfma_f32_16x16x32_bf16(a, b, acc[t], 0, 0, 0);
        }
    }
#pragma unroll
    for (int t = 0; t < 8; ++t) {
        int col = t * 16 + ln;
        float bi = bias[col];
#pragma unroll
        for (int i = 0; i < 4; ++i) {
            int gr = row0 + m0 + quad * 4 + i;
            if (gr < rows) out_bf[(size_t)gr * 128 + col] = f2bf(acc[t][i] + bi);
        }
    }
}

// ---------------- y projection: y[r][10] (+)= nx[r][:] @ Wp ----------------
template<bool ACCUM>
__global__ __launch_bounds__(256) void proj_y(
    const unsigned short* __restrict__ nx, const float* __restrict__ Wp,
    float* __restrict__ y, int rows)
{
    __shared__ float Wl[HID * NCLS];
    for (int i = threadIdx.x; i < HID * NCLS; i += 256) Wl[i] = Wp[i];
    __syncthreads();
    int r = blockIdx.x * 256 + threadIdx.x;
    if (r >= rows) return;
    float acc[NCLS];
#pragma unroll
    for (int c = 0; c < NCLS; ++c) acc[c] = 0.f;
    const unsigned short* xp = nx + (size_t)r * 128;
#pragma unroll 4
    for (int g = 0; g < 16; ++g) {
        ushort8 u = *(const ushort8*)(xp + g * 8);
#pragma unroll
        for (int j = 0; j < 8; ++j) {
            float xv = bf2f(u[j]);
            const float* w = Wl + (g * 8 + j) * NCLS;
#pragma unroll
            for (int c = 0; c < NCLS; ++c) acc[c] += xv * w[c];
        }
    }
    float* yp = y + (size_t)r * NCLS;
#pragma unroll
    for (int c = 0; c < NCLS; ++c) {
        if (ACCUM) yp[c] += acc[c];
        else yp[c] = acc[c];
    }
}

// ---------------- score scatter: score[b][:] += y[ori[m]][:] ----------------
__global__ __launch_bounds__(256) void score_scatter(
    const float* __restrict__ y, const int* __restrict__ ori,
    const int* __restrict__ batch, float* __restrict__ score)
{
    __shared__ float sc[NBATCH * NCLS];
    for (int i = threadIdx.x; i < NBATCH * NCLS; i += 256) sc[i] = 0.f;
    __syncthreads();
    int stride = gridDim.x * 256;
    for (int m = blockIdx.x * 256 + threadIdx.x; m < M_COPIES; m += stride) {
        int r = ori[m], b = batch[m];
        const float* yp = y + (size_t)r * NCLS;
#pragma unroll
        for (int c = 0; c < NCLS; ++c)
            __hip_atomic_fetch_add(&sc[b * NCLS + c], yp[c],
                                   __ATOMIC_RELAXED, __HIP_MEMORY_SCOPE_WORKGROUP);
    }
    __syncthreads();
    for (int i = threadIdx.x; i < NBATCH * NCLS; i += 256) gatomic_add(score + i, sc[i]);
}

__global__ void score_final(const float* __restrict__ score, const float* __restrict__ bp,
                            float* __restrict__ out)
{
    int t = threadIdx.x;
    if (t >= NBATCH * NCLS) return;
    int c = t % NCLS;
    out[t] = score[t] + bp[c] + bp[NCLS + c] + bp[2 * NCLS + c];
}

__global__ void fill_sentinel(float* out, int n, float enc) {
    int t = blockIdx.x * 64 + threadIdx.x;
    if (t < n) out[t] = enc;
}

// ---------------- helpers ----------------
static inline void build_csr_edge(const int* src, const int* dst, const int* remap,
                                  int nitem, int nseg, int* off, int* part,
                                  int* srcs, int* comps, hipStream_t stream) {
    int nb = (nseg + 255) / 256;
    (void)hipMemsetAsync(off, 0, (size_t)nseg * 4, stream);
    hist_k<<<(nitem + 255) / 256, 256, 0, stream>>>(dst, nitem, off);
    scan1_k<<<nb, 256, 0, stream>>>(off, nseg, part);
    scan2_k<<<1, 256, 0, stream>>>(part, nb);
    scan3_k<<<nb, 256, 0, stream>>>(off, nseg, part);
    fill_edge_k<<<(nitem + 255) / 256, 256, 0, stream>>>(src, dst, remap, nitem, off, srcs, comps);
}
static inline void build_csr_pool(const int* seg, int nitem, int nseg,
                                  int* off, int* part, int* items, hipStream_t stream) {
    int nb = (nseg + 255) / 256;
    (void)hipMemsetAsync(off, 0, (size_t)nseg * 4, stream);
    hist_k<<<(nitem + 255) / 256, 256, 0, stream>>>(seg, nitem, off);
    scan1_k<<<nb, 256, 0, stream>>>(off, nseg, part);
    scan2_k<<<1, 256, 0, stream>>>(part, nb);
    scan3_k<<<nb, 256, 0, stream>>>(off, nseg, part);
    fill_pool_k<<<(nitem + 255) / 256, 256, 0, stream>>>(seg, nitem, off, items);
}

// ---------------- entry ----------------
extern "C" void kernel_launch(void* const* d_in, const int* in_sizes, int n_in,
                              void* d_out, int out_size, void* d_ws, size_t ws_size,
                              hipStream_t stream) {
    const float* x_N    = (const float*)d_in[0];
    const float* We     = (const float*)d_in[1];
    const float* be     = (const float*)d_in[2];
    const float* Wg     = (const float*)d_in[3];
    const float* bg     = (const float*)d_in[4];
    const float* eps_g  = (const float*)d_in[5];
    const float* gam    = (const float*)d_in[6];
    const float* bet    = (const float*)d_in[7];
    const float* Wp     = (const float*)d_in[8];
    const float* bp     = (const float*)d_in[9];
    const int* ori_node = (const int*)d_in[10];
    const int* node2edge= (const int*)d_in[11];
    const int* eiN      = (const int*)d_in[12];
    const int* ori_edge = (const int*)d_in[13];
    const int* edge2node= (const int*)d_in[14];
    const int* eiE      = (const int*)d_in[15];
    const int* batch    = (const int*)d_in[16];

    char* p = (char*)d_ws;
    auto take = [&](size_t n) { char* r = p; p += (n + 255) & ~(size_t)255; return r; };
    unsigned short* Wt  = (unsigned short*)take((size_t)17 * 16384 * 2);
    unsigned short* Xb  = (unsigned short*)take((size_t)M_COPIES * 128 * 2);
    unsigned short* Xb2 = (unsigned short*)take((size_t)M_COPIES * 128 * 2);
    unsigned short* nx  = (unsigned short*)take((size_t)N_NODES * 128 * 2);
    unsigned short* ex  = (unsigned short*)take((size_t)N_EDGES * 128 * 2);
    float* y            = (float*)take((size_t)N_NODES * NCLS * 4);
    float* score        = (float*)take((size_t)NBATCH * NCLS * 4);
    int* offN           = (int*)take((size_t)M_COPIES * 4);
    int* offE           = (int*)take((size_t)M_COPIES * 4);
    int* off_n2e        = (int*)take((size_t)N_EDGES * 4);
    int* off_e2n        = (int*)take((size_t)N_NODES * 4);
    int* srcsN          = (int*)take((size_t)L_EDGES * 4);
    int* compsN         = (int*)take((size_t)L_EDGES * 4);
    int* srcsE          = (int*)take((size_t)L_EDGES * 4);
    int* compsE         = (int*)take((size_t)L_EDGES * 4);
    int* it_n2e         = (int*)take((size_t)M_COPIES * 4);
    int* it_e2n         = (int*)take((size_t)M_COPIES * 4);
    int* part           = (int*)take((size_t)2048 * 4);
    size_t need = (size_t)(p - (char*)d_ws);
    if (need > ws_size) {
        fill_sentinel<<<(out_size + 63) / 64, 64, 0, stream>>>(
            (float*)d_out, out_size, 1.0e9f + (float)ws_size);
        return;
    }

    prep_w<<<1088, 256, 0, stream>>>(We, Wg, Wt);
    (void)hipMemsetAsync(score, 0, (size_t)NBATCH * NCLS * 4, stream);

    build_csr_edge(eiN, eiN + L_EDGES, ori_node, L_EDGES, M_COPIES, offN, part, srcsN, compsN, stream);
    build_csr_edge(eiE, eiE + L_EDGES, ori_edge, L_EDGES, M_COPIES, offE, part, srcsE, compsE, stream);
    build_csr_pool(node2edge, M_COPIES, N_EDGES, off_n2e, part, it_n2e, stream);
    build_csr_pool(edge2node, M_COPIES, N_NODES, off_e2n, part, it_e2n, stream);

    gemm_embed<<<(N_NODES + 63) / 64, 256, 0, stream>>>(x_N, Wt, be, nx, N_NODES);
    proj_y<false><<<(N_NODES + 255) / 256, 256, 0, stream>>>(nx, Wp, y, N_NODES);

    const int MBLK = M_COPIES / 64;   // 6250 blocks of 256 threads
    for (int layer = 0; layer < 2; ++layer) {
        for (int dir = 0; dir < 2; ++dir) {
            int cj0 = layer * 4 + dir * 2;
            int cj1 = cj0 + 1;
            const unsigned short* base = (dir == 0) ? nx : ex;
            const int* selfI = (dir == 0) ? ori_node : ori_edge;
            const int* offD  = (dir == 0) ? offN : offE;
            const int* srcsD = (dir == 0) ? srcsN : srcsE;
            const int* compD = (dir == 0) ? compsN : compsE;

            fused_conv<true><<<MBLK, 256, 0, stream>>>(
                base, selfI, offD, compD, eps_g + cj0,
                Wt + (size_t)(1 + cj0 * 2) * 16384, bg + (cj0 * 2) * 128,
                Wt + (size_t)(1 + cj0 * 2 + 1) * 16384, bg + (cj0 * 2 + 1) * 128,
                gam + cj0 * 128, bet + cj0 * 128, Xb);
            fused_conv<false><<<MBLK, 256, 0, stream>>>(
                Xb, nullptr, offD, srcsD, eps_g + cj1,
                Wt + (size_t)(1 + cj1 * 2) * 16384, bg + (cj1 * 2) * 128,
                Wt + (size_t)(1 + cj1 * 2 + 1) * 16384, bg + (cj1 * 2 + 1) * 128,
                gam + cj1 * 128, bet + cj1 * 128, Xb2);
            if (dir == 0) {
                segsum_pool<<<(N_EDGES + 3) / 4, 256, 0, stream>>>(
                    Xb2, off_n2e, it_n2e, ex, N_EDGES);
            } else {
                segsum_pool<<<(N_NODES + 3) / 4, 256, 0, stream>>>(
                    Xb2, off_e2n, it_e2n, nx, N_NODES);
                proj_y<true><<<(N_NODES + 255) / 256, 256, 0, stream>>>(
                    nx, Wp + (layer + 1) * HID * NCLS, y, N_NODES);
            }
        }
    }
    score_scatter<<<256, 256, 0, stream>>>(y, ori_node, batch, score);
    score_final<<<1, 320, 0, stream>>>(score, bp, (float*)d_out);
}

// Round 2
// 1425.901 us; speedup vs baseline: 1.7428x; 1.7428x over previous
//
#include <hip/hip_runtime.h>
#include <hip/hip_bf16.h>

// ---------------- problem constants ----------------
#define HID 128
static const int N_NODES = 50000;
static const int N_EDGES = 20000;
static const int M_COPIES = 400000;
static const int L_EDGES = 800000;
static const int NBATCH = 32;
static const int NCLS = 10;
#define INV_STD 0.9999950000374997f   // 1/sqrt(1+1e-5)
#define IDX_CAP 384                   // per-block item cap (avg 128; global fallback)

typedef __attribute__((ext_vector_type(4))) float f32x4;
typedef __attribute__((ext_vector_type(8))) short short8;      // 8 bf16 lanes
typedef __attribute__((ext_vector_type(8))) unsigned short ushort8;
typedef __attribute__((ext_vector_type(4))) unsigned short u16x4;  // 'ushort4' collides with HIP header

__device__ __forceinline__ float bf2f(unsigned short u) {
    union { unsigned u; float f; } v; v.u = ((unsigned)u) << 16; return v.f;
}
__device__ __forceinline__ unsigned short f2bf(float f) {
    union { float f; unsigned u; } v; v.f = f;
    unsigned r = v.u + 0x7FFFu + ((v.u >> 16) & 1u);   // RNE
    return (unsigned short)(r >> 16);
}
__device__ __forceinline__ void gatomic_add(float* p, float v) {
    unsafeAtomicAdd(p, v);
}

// Swizzled Xs addressing: logical [chunk c][row r][8 bf16], 16 B per (c,r).
// byte = (c*1024 + r*16) ^ ((c&7)<<4) -> gather writes (c fast-varying across
// lanes) land on 8 distinct 16B slots instead of 1 (proven in R1: conflicts
// 2.88e7 -> 8e5). Read side stays dense (XOR is a bijection within 256B).
__device__ __forceinline__ unsigned short* xs_addr(unsigned short* Xs, int c, int r) {
    int byte = ((c * 64 + r) * 16) ^ ((c & 7) << 4);
    return (unsigned short*)((char*)Xs + byte);
}

// Async DMA of one wave's 1KB quarter of a 4KB W-eighth into LDS.
// Global layout (see prep_w) is byte-identical to the LDS image -> linear copy:
// conflict-free LDS writes, no VGPR round trip. Dest is wave-uniform base;
// HW adds lane*16.
__device__ __forceinline__ void stage8(const unsigned short* __restrict__ Wmat, int e,
                                       unsigned short* buf, int wave, int lane) {
    const char* g = (const char*)Wmat + ((size_t)e << 12) + (wave << 10) + (lane << 4);
    char* l = (char*)buf + (wave << 10);
    __builtin_amdgcn_global_load_lds(
        (const __attribute__((address_space(1))) unsigned int*)g,
        (__attribute__((address_space(3))) unsigned int*)l,
        16, 0, 0);
}

// 4 chained MFMAs: one eighth (16 out-channels) x full K for this wave's rows.
__device__ __forceinline__ void mfma4(const unsigned short* Ws, const short8* xv,
                                      f32x4& a, int quad, int ln) {
#pragma unroll
    for (int kc = 0; kc < 4; ++kc) {
        short8 wa = *(const short8*)(Ws + (((kc * 4 + quad) * 16) + ln) * 8);
        a = __builtin_amdgcn_mfma_f32_16x16x32_bf16(wa, xv[kc], a, 0, 0, 0);
    }
}

// ---------------- weight prep: eighth-linear layout ----------------
// Wt[mat] is 8 eighths x 2048 shorts; within an eighth, chunk (gg,n) at
// offset (gg*16+n)*8 holds W[k=gg*8..gg*8+7][col=h*16+n]. This is exactly
// the LDS image fused_conv's MFMAs read -> staging is a linear DMA.
__global__ __launch_bounds__(256) void prep_w(const float* __restrict__ We,
                                              const float* __restrict__ Wg,
                                              unsigned short* __restrict__ Wt) {
    int t = blockIdx.x * 256 + threadIdx.x;       // 17*16384
    if (t >= 17 * 16384) return;
    int mat = t >> 14, rem = t & 16383;
    int h = rem >> 11, r2 = rem & 2047;
    int gg = r2 >> 7, r3 = r2 & 127;
    int n = r3 >> 3, j = r3 & 7;
    int k = gg * 8 + j, col = h * 16 + n;
    const float* src = (mat == 0) ? We : (Wg + (size_t)(mat - 1) * 16384);
    Wt[t] = f2bf(src[k * 128 + col]);
}

// ---------------- CSR build ----------------
__global__ __launch_bounds__(256) void hist_k(const int* __restrict__ idx, int n,
                                              int* __restrict__ cnt) {
    int t = blockIdx.x * 256 + threadIdx.x;
    if (t < n) atomicAdd(&cnt[idx[t]], 1);
}

__global__ __launch_bounds__(256) void scan1_k(int* __restrict__ a, int n,
                                               int* __restrict__ part) {
    __shared__ int s[256];
    int i = blockIdx.x * 256 + threadIdx.x;
    int v = (i < n) ? a[i] : 0;
    s[threadIdx.x] = v;
    __syncthreads();
#pragma unroll
    for (int d = 1; d < 256; d <<= 1) {
        int t = (threadIdx.x >= d) ? s[threadIdx.x - d] : 0;
        __syncthreads();
        s[threadIdx.x] += t;
        __syncthreads();
    }
    if (i < n) a[i] = s[threadIdx.x] - v;
    if (threadIdx.x == 255) part[blockIdx.x] = s[255];
}

__global__ __launch_bounds__(256) void scan2_k(int* __restrict__ part, int nb) {
    __shared__ int s[256];
    __shared__ int carry;
    if (threadIdx.x == 0) carry = 0;
    __syncthreads();
    for (int base = 0; base < nb; base += 256) {
        int i = base + threadIdx.x;
        int v = (i < nb) ? part[i] : 0;
        s[threadIdx.x] = v;
        __syncthreads();
#pragma unroll
        for (int d = 1; d < 256; d <<= 1) {
            int t = (threadIdx.x >= d) ? s[threadIdx.x - d] : 0;
            __syncthreads();
            s[threadIdx.x] += t;
            __syncthreads();
        }
        if (i < nb) part[i] = carry + s[threadIdx.x] - v;
        __syncthreads();
        if (threadIdx.x == 0) carry += s[255];
        __syncthreads();
    }
}

__global__ __launch_bounds__(256) void scan3_k(int* __restrict__ a, int n,
                                               const int* __restrict__ part) {
    int i = blockIdx.x * 256 + threadIdx.x;
    if (i < n) a[i] += part[blockIdx.x];
}

__global__ __launch_bounds__(256) void fill_edge_k(
    const int* __restrict__ src, const int* __restrict__ dst,
    const int* __restrict__ remap, int n, int* __restrict__ off,
    int* __restrict__ srcs, int* __restrict__ comps) {
    int e = blockIdx.x * 256 + threadIdx.x;
    if (e >= n) return;
    int d = dst[e];
    int pos = atomicAdd(&off[d], 1);
    int s = src[e];
    srcs[pos] = s;
    comps[pos] = remap[s];
}

__global__ __launch_bounds__(256) void fill_pool_k(
    const int* __restrict__ seg, int n, int* __restrict__ off,
    int* __restrict__ items) {
    int m = blockIdx.x * 256 + threadIdx.x;
    if (m >= n) return;
    int pos = atomicAdd(&off[seg[m]], 1);
    items[pos] = m;
}

// ---------------- pool segment sum: wave-per-segment, 4 rows in flight ----------------
__global__ __launch_bounds__(256) void segsum_pool(
    const unsigned short* __restrict__ tbl, const int* __restrict__ off,
    const int* __restrict__ items, unsigned short* __restrict__ out, int nseg)
{
    int wave = threadIdx.x >> 6, lane = threadIdx.x & 63;
    int seg = blockIdx.x * 4 + wave;
    if (seg >= nseg) return;
    int start = (seg == 0) ? 0 : off[seg - 1];
    int end = off[seg];
    int g = lane & 15, sub = lane >> 4;
    float a[8] = {0.f, 0.f, 0.f, 0.f, 0.f, 0.f, 0.f, 0.f};
    for (int p = start + sub; p < end; p += 4) {
        int r = items[p];                          // broadcast across the 16 g-lanes
        ushort8 v = *(const ushort8*)(tbl + (size_t)r * 128 + g * 8);
#pragma unroll
        for (int j = 0; j < 8; ++j) a[j] += bf2f(v[j]);
    }
#pragma unroll
    for (int j = 0; j < 8; ++j) {
        a[j] += __shfl_xor(a[j], 16, 64);
        a[j] += __shfl_xor(a[j], 32, 64);
    }
    if (sub == 0) {
        ushort8 ov;
#pragma unroll
        for (int j = 0; j < 8; ++j) ov[j] = f2bf(fmaxf(a[j], 0.f));
        *(ushort8*)(out + (size_t)seg * 128 + g * 8) = ov;
    }
}

// ---------------- fused GIN conv: 256 thr / 64 rows ----------------
// gather-segsum + linear1+ReLU + linear2+BN(+ReLU).
// W staged in LDS (shared across the 4 waves) via double-buffered 4KB eighths
// DMA'd with global_load_lds from the eighth-linear Wt image: conflict-free
// writes, no staging VALU, 1 barrier per eighth (17 total vs 34 baseline).
// Xs is XOR-swizzled (R1-proven) to kill the 16-way gather-write conflict.
template<bool CONV0>
__global__ __launch_bounds__(256, 6) void fused_conv(
    const unsigned short* __restrict__ tbl,
    const int* __restrict__ self_idx,
    const int* __restrict__ off, const int* __restrict__ items,
    const float* __restrict__ eps_ptr,
    const unsigned short* __restrict__ W1t, const float* __restrict__ b1,
    const unsigned short* __restrict__ W2t, const float* __restrict__ b2,
    const float* __restrict__ gam, const float* __restrict__ bet,
    unsigned short* __restrict__ out)
{
    __shared__ __align__(16) unsigned short Xs[16 * 64 * 8];  // 16 KB, swizzled
    __shared__ __align__(16) unsigned short Wsb[2][2048];     // 2 x 4 KB eighth buffers
    __shared__ int sIdx[IDX_CAP];                             // 1.5 KB
    __shared__ int meta[192];                                 // 0.75 KB
    const int tid = threadIdx.x;
    const int row0 = blockIdx.x * 64;
    const int wave = tid >> 6, lane = tid & 63;

    // issue W1 eighth-0 DMA immediately: fully hidden under the gather
    stage8(W1t, 0, Wsb[0], wave, lane);

    const int bstart = (row0 == 0) ? 0 : off[row0 - 1];
    const int cnt = off[row0 + 63] - bstart;
    const bool useLds = (cnt <= IDX_CAP);

    if (tid < 64) {
        int gr = row0 + tid;
        meta[tid]       = (gr == 0) ? 0 : off[gr - 1];
        meta[64 + tid]  = off[gr];
        meta[128 + tid] = CONV0 ? self_idx[gr] : gr;
    }
    if (useLds)
        for (int i = tid; i < cnt; i += 256) sIdx[i] = items[bstart + i];
    __syncthreads();

    // ---- gather: thread (rb,g) walks rows rb+16i; idx from LDS, 2-wide loads ----
    const float e = 1.0f + eps_ptr[0];
    const int g = tid & 15;
    const int rb = tid >> 4;        // 0..15
#pragma unroll
    for (int i = 0; i < 4; ++i) {
        int r = rb + 16 * i;
        int start = meta[r], end = meta[64 + r], self = meta[128 + r];
        float a[8];
        ushort8 u = *(const ushort8*)(tbl + (size_t)self * 128 + g * 8);
#pragma unroll
        for (int j = 0; j < 8; ++j) a[j] = e * bf2f(u[j]);
        if (useLds) {
            int pos = start - bstart, pe = end - bstart;
            for (; pos + 2 <= pe; pos += 2) {
                int i0 = sIdx[pos], i1 = sIdx[pos + 1];
                ushort8 v0 = *(const ushort8*)(tbl + (size_t)i0 * 128 + g * 8);
                ushort8 v1 = *(const ushort8*)(tbl + (size_t)i1 * 128 + g * 8);
#pragma unroll
                for (int j = 0; j < 8; ++j) a[j] += bf2f(v0[j]) + bf2f(v1[j]);
            }
            if (pos < pe) {
                int i0 = sIdx[pos];
                ushort8 v0 = *(const ushort8*)(tbl + (size_t)i0 * 128 + g * 8);
#pragma unroll
                for (int j = 0; j < 8; ++j) a[j] += bf2f(v0[j]);
            }
        } else {
            for (int pos = start; pos < end; ++pos) {
                int rr = items[pos];
                ushort8 v = *(const ushort8*)(tbl + (size_t)rr * 128 + g * 8);
#pragma unroll
                for (int j = 0; j < 8; ++j) a[j] += bf2f(v[j]);
            }
        }
        ushort8 xv;
#pragma unroll
        for (int j = 0; j < 8; ++j) xv[j] = f2bf(a[j]);
        *(ushort8*)xs_addr(Xs, g, r) = xv;
    }
    __syncthreads();   // Xs gather writes ready + Wsb[0] DMA drained (vmcnt(0))

    const int ln = lane & 15, quad = lane >> 4;
    const int row = wave * 16 + ln;   // wave-private X/H row (4 waves x 16 = 64)

    // hoist X fragments (wave reads only its own rows)
    short8 xb[4];
#pragma unroll
    for (int kc = 0; kc < 4; ++kc)
        xb[kc] = *(const short8*)xs_addr(Xs, kc * 4 + quad, row);

    f32x4 acc[8];
#pragma unroll
    for (int t = 0; t < 8; ++t) acc[t] = (f32x4){0.f, 0.f, 0.f, 0.f};

    // ---- GEMM 1: double-buffered eighths; e=7 prefetches W2 eighth 0 ----
#pragma unroll
    for (int e8 = 0; e8 < 8; ++e8) {
        if (e8 < 7) stage8(W1t, e8 + 1, Wsb[(e8 + 1) & 1], wave, lane);
        else        stage8(W2t, 0,      Wsb[0],            wave, lane);
        mfma4(Wsb[e8 & 1], xb, acc[e8], quad, ln);
        __syncthreads();   // readers of next buffer wait for its DMA; writers of
                           // the buffer just read wait for the reads (next iter)
    }

    // h = relu(acc + b1) -> Xs (own rows only; same-wave LDS ordering suffices)
    {
        const int j0 = (quad & 1) * 4;
#pragma unroll
        for (int t = 0; t < 8; ++t) {
            int p0 = t * 16 + quad * 4;
            f32x4 bv = *(const f32x4*)(b1 + p0);
            u16x4 hp;
#pragma unroll
            for (int i = 0; i < 4; ++i) hp[i] = f2bf(fmaxf(acc[t][i] + bv[i], 0.f));
            *(u16x4*)((char*)xs_addr(Xs, p0 >> 3, row) + j0 * 2) = hp;
        }
    }

    // hoist H fragments (own rows, written by own wave's lanes)
    short8 hb[4];
#pragma unroll
    for (int kc = 0; kc < 4; ++kc)
        hb[kc] = *(const short8*)xs_addr(Xs, kc * 4 + quad, row);

#pragma unroll
    for (int t = 0; t < 8; ++t) acc[t] = (f32x4){0.f, 0.f, 0.f, 0.f};

    // ---- GEMM 2: Wsb[0] already holds W2 eighth 0 (prefetched at e=7) ----
#pragma unroll
    for (int f = 0; f < 8; ++f) {
        if (f < 7) stage8(W2t, f + 1, Wsb[(f + 1) & 1], wave, lane);
        mfma4(Wsb[f & 1], hb, acc[f], quad, ln);
        if (f < 7) __syncthreads();
    }

    // epilogue: lane holds out[row0+row][n0..n0+3] -> 8B stores
    const int m = row0 + row;
#pragma unroll
    for (int t = 0; t < 8; ++t) {
        int n0 = t * 16 + quad * 4;
        f32x4 bv = *(const f32x4*)(b2 + n0);
        f32x4 gv = *(const f32x4*)(gam + n0);
        f32x4 tv = *(const f32x4*)(bet + n0);
        u16x4 op;
#pragma unroll
        for (int i = 0; i < 4; ++i) {
            float h = acc[t][i] + bv[i];
            h = gv[i] * h * INV_STD + tv[i];
            if (CONV0) h = fmaxf(h, 0.f);
            op[i] = f2bf(h);
        }
        *(u16x4*)(out + (size_t)m * 128 + n0) = op;
    }
}

// ---------------- embedding GEMM (f32 in): out = in @ W + b ----------------
__global__ __launch_bounds__(256) void gemm_embed(
    const float* __restrict__ in, const unsigned short* __restrict__ Wt,
    const float* __restrict__ bias, unsigned short* __restrict__ out_bf, int rows)
{
    __shared__ __align__(16) unsigned short Xs[16 * 64 * 8];
    __shared__ __align__(16) unsigned short Ws[16 * 128 * 8];
    int tid = threadIdx.x;
    int row0 = blockIdx.x * 64;
#pragma unroll
    for (int i = 0; i < 8; ++i) {
        int chunk = tid + i * 256;
        int n = chunk >> 4, g = chunk & 15;
        // source: eighth-linear Wt -> chunk (g, n) at (n>>4)*2048 + g*128 + (n&15)*8
        *(short8*)(Ws + (g * 128 + n) * 8) =
            *(const short8*)(Wt + (n >> 4) * 2048 + g * 128 + (n & 15) * 8);
    }
#pragma unroll
    for (int i = 0; i < 4; ++i) {
        int chunk = tid + i * 256;
        int r = chunk >> 4, g = chunk & 15;
        int gr = row0 + r;
        ushort8 v;
        if (gr < rows) {
            const float* p = in + (size_t)gr * 128 + g * 8;
            f32x4 a0 = *(const f32x4*)p;
            f32x4 a1 = *(const f32x4*)(p + 4);
#pragma unroll
            for (int j = 0; j < 4; ++j) { v[j] = f2bf(a0[j]); v[4 + j] = f2bf(a1[j]); }
        } else {
#pragma unroll
            for (int j = 0; j < 8; ++j) v[j] = 0;
        }
        *(ushort8*)(Xs + (g * 64 + r) * 8) = v;
    }
    __syncthreads();
    int wave = tid >> 6, lane = tid & 63;
    int m0 = wave * 16;
    int ln = lane & 15, quad = lane >> 4;
    f32x4 acc[8];
#pragma unroll
    for (int t = 0; t < 8; ++t) acc[t] = (f32x4){0.f, 0.f, 0.f, 0.f};
#pragma unroll
    for (int kc = 0; kc < 4; ++kc) {
        int g = kc * 4 + quad;
        short8 a = *(const short8*)(Xs + (g * 64 + m0 + ln) * 8);
#pragma unroll
        for (int t = 0; t < 8; ++t) {
            short8 b = *(const short8*)(Ws + (g * 128 + t * 16 + ln) * 8);
            acc[t] = __builtin_amdgcn_mfma_f32_16x16x32_bf16(a, b, acc[t], 0, 0, 0);
        }
    }
#pragma unroll
    for (int t = 0; t < 8; ++t) {
        int col = t * 16 + ln;
        float bi = bias[col];
#pragma unroll
        for (int i = 0; i < 4; ++i) {
            int gr = row0 + m0 + quad * 4 + i;
            if (gr < rows) out_bf[(size_t)gr * 128 + col] = f2bf(acc[t][i] + bi);
        }
    }
}

// ---------------- y projection: y[r][10] (+)= nx[r][:] @ Wp ----------------
template<bool ACCUM>
__global__ __launch_bounds__(256) void proj_y(
    const unsigned short* __restrict__ nx, const float* __restrict__ Wp,
    float* __restrict__ y, int rows)
{
    __shared__ float Wl[HID * NCLS];
    for (int i = threadIdx.x; i < HID * NCLS; i += 256) Wl[i] = Wp[i];
    __syncthreads();
    int r = blockIdx.x * 256 + threadIdx.x;
    if (r >= rows) return;
    float acc[NCLS];
#pragma unroll
    for (int c = 0; c < NCLS; ++c) acc[c] = 0.f;
    const unsigned short* xp = nx + (size_t)r * 128;
#pragma unroll 4
    for (int g = 0; g < 16; ++g) {
        ushort8 u = *(const ushort8*)(xp + g * 8);
#pragma unroll
        for (int j = 0; j < 8; ++j) {
            float xv = bf2f(u[j]);
            const float* w = Wl + (g * 8 + j) * NCLS;
#pragma unroll
            for (int c = 0; c < NCLS; ++c) acc[c] += xv * w[c];
        }
    }
    float* yp = y + (size_t)r * NCLS;
#pragma unroll
    for (int c = 0; c < NCLS; ++c) {
        if (ACCUM) yp[c] += acc[c];
        else yp[c] = acc[c];
    }
}

// ---------------- score scatter: score[b][:] += y[ori[m]][:] ----------------
__global__ __launch_bounds__(256) void score_scatter(
    const float* __restrict__ y, const int* __restrict__ ori,
    const int* __restrict__ batch, float* __restrict__ score)
{
    __shared__ float sc[NBATCH * NCLS];
    for (int i = threadIdx.x; i < NBATCH * NCLS; i += 256) sc[i] = 0.f;
    __syncthreads();
    int stride = gridDim.x * 256;
    for (int m = blockIdx.x * 256 + threadIdx.x; m < M_COPIES; m += stride) {
        int r = ori[m], b = batch[m];
        const float* yp = y + (size_t)r * NCLS;
#pragma unroll
        for (int c = 0; c < NCLS; ++c)
            __hip_atomic_fetch_add(&sc[b * NCLS + c], yp[c],
                                   __ATOMIC_RELAXED, __HIP_MEMORY_SCOPE_WORKGROUP);
    }
    __syncthreads();
    for (int i = threadIdx.x; i < NBATCH * NCLS; i += 256) gatomic_add(score + i, sc[i]);
}

__global__ void score_final(const float* __restrict__ score, const float* __restrict__ bp,
                            float* __restrict__ out)
{
    int t = threadIdx.x;
    if (t >= NBATCH * NCLS) return;
    int c = t % NCLS;
    out[t] = score[t] + bp[c] + bp[NCLS + c] + bp[2 * NCLS + c];
}

__global__ void fill_sentinel(float* out, int n, float enc) {
    int t = blockIdx.x * 64 + threadIdx.x;
    if (t < n) out[t] = enc;
}

// ---------------- helpers ----------------
static inline void build_csr_edge(const int* src, const int* dst, const int* remap,
                                  int nitem, int nseg, int* off, int* part,
                                  int* srcs, int* comps, hipStream_t stream) {
    int nb = (nseg + 255) / 256;
    (void)hipMemsetAsync(off, 0, (size_t)nseg * 4, stream);
    hist_k<<<(nitem + 255) / 256, 256, 0, stream>>>(dst, nitem, off);
    scan1_k<<<nb, 256, 0, stream>>>(off, nseg, part);
    scan2_k<<<1, 256, 0, stream>>>(part, nb);
    scan3_k<<<nb, 256, 0, stream>>>(off, nseg, part);
    fill_edge_k<<<(nitem + 255) / 256, 256, 0, stream>>>(src, dst, remap, nitem, off, srcs, comps);
}
static inline void build_csr_pool(const int* seg, int nitem, int nseg,
                                  int* off, int* part, int* items, hipStream_t stream) {
    int nb = (nseg + 255) / 256;
    (void)hipMemsetAsync(off, 0, (size_t)nseg * 4, stream);
    hist_k<<<(nitem + 255) / 256, 256, 0, stream>>>(seg, nitem, off);
    scan1_k<<<nb, 256, 0, stream>>>(off, nseg, part);
    scan2_k<<<1, 256, 0, stream>>>(part, nb);
    scan3_k<<<nb, 256, 0, stream>>>(off, nseg, part);
    fill_pool_k<<<(nitem + 255) / 256, 256, 0, stream>>>(seg, nitem, off, items);
}

// ---------------- entry ----------------
extern "C" void kernel_launch(void* const* d_in, const int* in_sizes, int n_in,
                              void* d_out, int out_size, void* d_ws, size_t ws_size,
                              hipStream_t stream) {
    const float* x_N    = (const float*)d_in[0];
    const float* We     = (const float*)d_in[1];
    const float* be     = (const float*)d_in[2];
    const float* Wg     = (const float*)d_in[3];
    const float* bg     = (const float*)d_in[4];
    const float* eps_g  = (const float*)d_in[5];
    const float* gam    = (const float*)d_in[6];
    const float* bet    = (const float*)d_in[7];
    const float* Wp     = (const float*)d_in[8];
    const float* bp     = (const float*)d_in[9];
    const int* ori_node = (const int*)d_in[10];
    const int* node2edge= (const int*)d_in[11];
    const int* eiN      = (const int*)d_in[12];
    const int* ori_edge = (const int*)d_in[13];
    const int* edge2node= (const int*)d_in[14];
    const int* eiE      = (const int*)d_in[15];
    const int* batch    = (const int*)d_in[16];

    char* p = (char*)d_ws;
    auto take = [&](size_t n) { char* r = p; p += (n + 255) & ~(size_t)255; return r; };
    unsigned short* Wt  = (unsigned short*)take((size_t)17 * 16384 * 2);
    unsigned short* Xb  = (unsigned short*)take((size_t)M_COPIES * 128 * 2);
    unsigned short* Xb2 = (unsigned short*)take((size_t)M_COPIES * 128 * 2);
    unsigned short* nx  = (unsigned short*)take((size_t)N_NODES * 128 * 2);
    unsigned short* ex  = (unsigned short*)take((size_t)N_EDGES * 128 * 2);
    float* y            = (float*)take((size_t)N_NODES * NCLS * 4);
    float* score        = (float*)take((size_t)NBATCH * NCLS * 4);
    int* offN           = (int*)take((size_t)M_COPIES * 4);
    int* offE           = (int*)take((size_t)M_COPIES * 4);
    int* off_n2e        = (int*)take((size_t)N_EDGES * 4);
    int* off_e2n        = (int*)take((size_t)N_NODES * 4);
    int* srcsN          = (int*)take((size_t)L_EDGES * 4);
    int* compsN         = (int*)take((size_t)L_EDGES * 4);
    int* srcsE          = (int*)take((size_t)L_EDGES * 4);
    int* compsE         = (int*)take((size_t)L_EDGES * 4);
    int* it_n2e         = (int*)take((size_t)M_COPIES * 4);
    int* it_e2n         = (int*)take((size_t)M_COPIES * 4);
    int* part           = (int*)take((size_t)2048 * 4);
    size_t need = (size_t)(p - (char*)d_ws);
    if (need > ws_size) {
        fill_sentinel<<<(out_size + 63) / 64, 64, 0, stream>>>(
            (float*)d_out, out_size, 1.0e9f + (float)ws_size);
        return;
    }

    prep_w<<<1088, 256, 0, stream>>>(We, Wg, Wt);
    (void)hipMemsetAsync(score, 0, (size_t)NBATCH * NCLS * 4, stream);

    build_csr_edge(eiN, eiN + L_EDGES, ori_node, L_EDGES, M_COPIES, offN, part, srcsN, compsN, stream);
    build_csr_edge(eiE, eiE + L_EDGES, ori_edge, L_EDGES, M_COPIES, offE, part, srcsE, compsE, stream);
    build_csr_pool(node2edge, M_COPIES, N_EDGES, off_n2e, part, it_n2e, stream);
    build_csr_pool(edge2node, M_COPIES, N_NODES, off_e2n, part, it_e2n, stream);

    gemm_embed<<<(N_NODES + 63) / 64, 256, 0, stream>>>(x_N, Wt, be, nx, N_NODES);
    proj_y<false><<<(N_NODES + 255) / 256, 256, 0, stream>>>(nx, Wp, y, N_NODES);

    const int MBLK = M_COPIES / 64;   // 6250 blocks of 256 threads
    for (int layer = 0; layer < 2; ++layer) {
        for (int dir = 0; dir < 2; ++dir) {
            int cj0 = layer * 4 + dir * 2;
            int cj1 = cj0 + 1;
            const unsigned short* base = (dir == 0) ? nx : ex;
            const int* selfI = (dir == 0) ? ori_node : ori_edge;
            const int* offD  = (dir == 0) ? offN : offE;
            const int* srcsD = (dir == 0) ? srcsN : srcsE;
            const int* compD = (dir == 0) ? compsN : compsE;

            fused_conv<true><<<MBLK, 256, 0, stream>>>(
                base, selfI, offD, compD, eps_g + cj0,
                Wt + (size_t)(1 + cj0 * 2) * 16384, bg + (cj0 * 2) * 128,
                Wt + (size_t)(1 + cj0 * 2 + 1) * 16384, bg + (cj0 * 2 + 1) * 128,
                gam + cj0 * 128, bet + cj0 * 128, Xb);
            fused_conv<false><<<MBLK, 256, 0, stream>>>(
                Xb, nullptr, offD, srcsD, eps_g + cj1,
                Wt + (size_t)(1 + cj1 * 2) * 16384, bg + (cj1 * 2) * 128,
                Wt + (size_t)(1 + cj1 * 2 + 1) * 16384, bg + (cj1 * 2 + 1) * 128,
                gam + cj1 * 128, bet + cj1 * 128, Xb2);
            if (dir == 0) {
                segsum_pool<<<(N_EDGES + 3) / 4, 256, 0, stream>>>(
                    Xb2, off_n2e, it_n2e, ex, N_EDGES);
            } else {
                segsum_pool<<<(N_NODES + 3) / 4, 256, 0, stream>>>(
                    Xb2, off_e2n, it_e2n, nx, N_NODES);
                proj_y<true><<<(N_NODES + 255) / 256, 256, 0, stream>>>(
                    nx, Wp + (layer + 1) * HID * NCLS, y, N_NODES);
            }
        }
    }
    score_scatter<<<256, 256, 0, stream>>>(y, ori_node, batch, score);
    score_final<<<1, 320, 0, stream>>>(score, bp, (float*)d_out);
}

// Round 3
// 1418.164 us; speedup vs baseline: 1.7523x; 1.0055x over previous
//
#include <hip/hip_runtime.h>
#include <hip/hip_bf16.h>

// ---------------- problem constants ----------------
#define HID 128
static const int N_NODES = 50000;
static const int N_EDGES = 20000;
static const int M_COPIES = 400000;
static const int L_EDGES = 800000;
static const int NBATCH = 32;
static const int NCLS = 10;
#define INV_STD 0.9999950000374997f   // 1/sqrt(1+1e-5)
#define IDX_CAP 384                   // per-block item cap (avg 128; global fallback)

typedef __attribute__((ext_vector_type(4))) float f32x4;
typedef __attribute__((ext_vector_type(8))) short short8;      // 8 bf16 lanes
typedef __attribute__((ext_vector_type(8))) unsigned short ushort8;
typedef __attribute__((ext_vector_type(4))) unsigned short u16x4;  // 'ushort4' collides with HIP header

__device__ __forceinline__ float bf2f(unsigned short u) {
    union { unsigned u; float f; } v; v.u = ((unsigned)u) << 16; return v.f;
}
__device__ __forceinline__ unsigned short f2bf(float f) {
    union { float f; unsigned u; } v; v.f = f;
    unsigned r = v.u + 0x7FFFu + ((v.u >> 16) & 1u);   // RNE
    return (unsigned short)(r >> 16);
}
__device__ __forceinline__ void gatomic_add(float* p, float v) {
    unsafeAtomicAdd(p, v);
}

// Swizzled Xs addressing: logical [chunk c][row r][8 bf16], 16 B per (c,r).
// byte = (c*1024 + r*16) ^ ((c&7)<<4) -> gather writes (c fast-varying across
// lanes) land on 8 distinct 16B slots instead of 1 (proven: conflicts 2.88e7->8e5).
__device__ __forceinline__ unsigned short* xs_addr(unsigned short* Xs, int c, int r) {
    int byte = ((c * 64 + r) * 16) ^ ((c & 7) << 4);
    return (unsigned short*)((char*)Xs + byte);
}

// Async DMA of one wave's 1KB quarter of a 4KB W-eighth into LDS (linear copy
// from the eighth-linear Wt image: conflict-free writes, no VGPR round trip).
__device__ __forceinline__ void stage8(const unsigned short* __restrict__ Wmat, int e,
                                       unsigned short* buf, int wave, int lane) {
    const char* g = (const char*)Wmat + ((size_t)e << 12) + (wave << 10) + (lane << 4);
    char* l = (char*)buf + (wave << 10);
    __builtin_amdgcn_global_load_lds(
        (const __attribute__((address_space(1))) unsigned int*)g,
        (__attribute__((address_space(3))) unsigned int*)l,
        16, 0, 0);
}

// Counted-vmcnt barrier (T4): keep N DMAs in flight ACROSS the barrier.
// vmem ledger in the GEMM loops is exact: only stage8 DMAs are outstanding
// (gather loads drained by the gather-end __syncthreads; bias loads are
// consumed-on-use so in-order vmcnt retire clears them).
template<int N>
__device__ __forceinline__ void pipe_barrier() {
    if constexpr (N == 0) asm volatile("s_waitcnt vmcnt(0)" ::: "memory");
    else                  asm volatile("s_waitcnt vmcnt(1)" ::: "memory");
    __builtin_amdgcn_s_barrier();
    asm volatile("" ::: "memory");
}

// 4 chained MFMAs: one eighth (16 out-channels) x full K for this wave's rows.
__device__ __forceinline__ void mfma4(const unsigned short* Ws, const short8* xv,
                                      f32x4& a, int quad, int ln) {
#pragma unroll
    for (int kc = 0; kc < 4; ++kc) {
        short8 wa = *(const short8*)(Ws + (((kc * 4 + quad) * 16) + ln) * 8);
        a = __builtin_amdgcn_mfma_f32_16x16x32_bf16(wa, xv[kc], a, 0, 0, 0);
    }
}

// ---------------- weight prep: eighth-linear layout ----------------
// Wt[mat] is 8 eighths x 2048 shorts; within an eighth, chunk (gg,n) at
// offset (gg*16+n)*8 holds W[k=gg*8..gg*8+7][col=h*16+n] -> LDS image == global.
__global__ __launch_bounds__(256) void prep_w(const float* __restrict__ We,
                                              const float* __restrict__ Wg,
                                              unsigned short* __restrict__ Wt) {
    int t = blockIdx.x * 256 + threadIdx.x;       // 17*16384
    if (t >= 17 * 16384) return;
    int mat = t >> 14, rem = t & 16383;
    int h = rem >> 11, r2 = rem & 2047;
    int gg = r2 >> 7, r3 = r2 & 127;
    int n = r3 >> 3, j = r3 & 7;
    int k = gg * 8 + j, col = h * 16 + n;
    const float* src = (mat == 0) ? We : (Wg + (size_t)(mat - 1) * 16384);
    Wt[t] = f2bf(src[k * 128 + col]);
}

// ---------------- CSR build (pairwise-fused kernels) ----------------
__global__ __launch_bounds__(256) void hist2_k(
    const int* __restrict__ iA, int nA, int* __restrict__ cA,
    const int* __restrict__ iB, int nB, int* __restrict__ cB) {
    int t = blockIdx.x * 256 + threadIdx.x;
    if (t < nA) atomicAdd(&cA[iA[t]], 1);
    if (t < nB) atomicAdd(&cB[iB[t]], 1);
}

__global__ __launch_bounds__(256) void scan1d_k(
    int* __restrict__ a0, int n0, int* __restrict__ p0,
    int* __restrict__ a1, int n1, int* __restrict__ p1) {
    int* a    = blockIdx.y ? a1 : a0;
    int n     = blockIdx.y ? n1 : n0;
    int* part = blockIdx.y ? p1 : p0;
    if ((int)(blockIdx.x * 256) >= n) return;   // uniform per block
    __shared__ int s[256];
    int i = blockIdx.x * 256 + threadIdx.x;
    int v = (i < n) ? a[i] : 0;
    s[threadIdx.x] = v;
    __syncthreads();
#pragma unroll
    for (int d = 1; d < 256; d <<= 1) {
        int t = (threadIdx.x >= d) ? s[threadIdx.x - d] : 0;
        __syncthreads();
        s[threadIdx.x] += t;
        __syncthreads();
    }
    if (i < n) a[i] = s[threadIdx.x] - v;
    if (threadIdx.x == 255) part[blockIdx.x] = s[255];
}

__global__ __launch_bounds__(256) void scan2d_k(
    int* __restrict__ p0, int nb0, int* __restrict__ p1, int nb1) {
    int* part = blockIdx.x ? p1 : p0;
    int nb    = blockIdx.x ? nb1 : nb0;
    __shared__ int s[256];
    __shared__ int carry;
    if (threadIdx.x == 0) carry = 0;
    __syncthreads();
    for (int base = 0; base < nb; base += 256) {
        int i = base + threadIdx.x;
        int v = (i < nb) ? part[i] : 0;
        s[threadIdx.x] = v;
        __syncthreads();
#pragma unroll
        for (int d = 1; d < 256; d <<= 1) {
            int t = (threadIdx.x >= d) ? s[threadIdx.x - d] : 0;
            __syncthreads();
            s[threadIdx.x] += t;
            __syncthreads();
        }
        if (i < nb) part[i] = carry + s[threadIdx.x] - v;
        __syncthreads();
        if (threadIdx.x == 0) carry += s[255];
        __syncthreads();
    }
}

__global__ __launch_bounds__(256) void scan3d_k(
    int* __restrict__ a0, int n0, const int* __restrict__ p0,
    int* __restrict__ a1, int n1, const int* __restrict__ p1) {
    int* a          = blockIdx.y ? a1 : a0;
    int n           = blockIdx.y ? n1 : n0;
    const int* part = blockIdx.y ? p1 : p0;
    int i = blockIdx.x * 256 + threadIdx.x;
    if (i < n) a[i] += part[blockIdx.x];
}

__global__ __launch_bounds__(256) void fill_edge2_k(
    const int* __restrict__ sA, const int* __restrict__ dA, const int* __restrict__ rA,
    int nA, int* __restrict__ oA, int* __restrict__ ssA, int* __restrict__ ccA,
    const int* __restrict__ sB, const int* __restrict__ dB, const int* __restrict__ rB,
    int nB, int* __restrict__ oB, int* __restrict__ ssB, int* __restrict__ ccB) {
    int t = blockIdx.x * 256 + threadIdx.x;
    if (t < nA) {
        int d = dA[t]; int pos = atomicAdd(&oA[d], 1);
        int s = sA[t]; ssA[pos] = s; ccA[pos] = rA[s];
    }
    if (t < nB) {
        int d = dB[t]; int pos = atomicAdd(&oB[d], 1);
        int s = sB[t]; ssB[pos] = s; ccB[pos] = rB[s];
    }
}

__global__ __launch_bounds__(256) void fill_pool2_k(
    const int* __restrict__ gA, int nA, int* __restrict__ oA, int* __restrict__ itA,
    const int* __restrict__ gB, int nB, int* __restrict__ oB, int* __restrict__ itB) {
    int t = blockIdx.x * 256 + threadIdx.x;
    if (t < nA) { int pos = atomicAdd(&oA[gA[t]], 1); itA[pos] = t; }
    if (t < nB) { int pos = atomicAdd(&oB[gB[t]], 1); itB[pos] = t; }
}

// ---------------- pool segment sum: wave-per-segment, 4 rows in flight ----------------
__global__ __launch_bounds__(256) void segsum_pool(
    const unsigned short* __restrict__ tbl, const int* __restrict__ off,
    const int* __restrict__ items, unsigned short* __restrict__ out, int nseg)
{
    int wave = threadIdx.x >> 6, lane = threadIdx.x & 63;
    int seg = blockIdx.x * 4 + wave;
    if (seg >= nseg) return;
    int start = (seg == 0) ? 0 : off[seg - 1];
    int end = off[seg];
    int g = lane & 15, sub = lane >> 4;
    float a[8] = {0.f, 0.f, 0.f, 0.f, 0.f, 0.f, 0.f, 0.f};
    for (int p = start + sub; p < end; p += 4) {
        int r = items[p];                          // broadcast across the 16 g-lanes
        ushort8 v = *(const ushort8*)(tbl + (size_t)r * 128 + g * 8);
#pragma unroll
        for (int j = 0; j < 8; ++j) a[j] += bf2f(v[j]);
    }
#pragma unroll
    for (int j = 0; j < 8; ++j) {
        a[j] += __shfl_xor(a[j], 16, 64);
        a[j] += __shfl_xor(a[j], 32, 64);
    }
    if (sub == 0) {
        ushort8 ov;
#pragma unroll
        for (int j = 0; j < 8; ++j) ov[j] = f2bf(fmaxf(a[j], 0.f));
        *(ushort8*)(out + (size_t)seg * 128 + g * 8) = ov;
    }
}

// ---------------- fused GIN conv: 256 thr / 64 rows ----------------
// gather-segsum + linear1+ReLU + linear2+BN(+ReLU).
// (a) 4-row-interleaved gather: one ballot-terminated loop, 4 clamped-index
//     loads in flight per step (was: 4 serial divergent loops, 2-wide).
// (b) W staged via 3x4KB buffers, prefetch depth 2, counted vmcnt(1) + raw
//     s_barrier: DMA latency rides across barriers (T3/T4), never drained
//     in-loop. DMA(s) is retired by the vmcnt(1) at end of iter s-1.
template<bool CONV0>
__global__ __launch_bounds__(256, 5) void fused_conv(
    const unsigned short* __restrict__ tbl,
    const int* __restrict__ self_idx,
    const int* __restrict__ off, const int* __restrict__ items,
    const float* __restrict__ eps_ptr,
    const unsigned short* __restrict__ W1t, const float* __restrict__ b1,
    const unsigned short* __restrict__ W2t, const float* __restrict__ b2,
    const float* __restrict__ gam, const float* __restrict__ bet,
    unsigned short* __restrict__ out)
{
    __shared__ __align__(16) unsigned short Xs[16 * 64 * 8];  // 16 KB, swizzled
    __shared__ __align__(16) unsigned short Wsb[3][2048];     // 3 x 4 KB eighth buffers
    __shared__ int sIdx[IDX_CAP];                             // 1.5 KB
    __shared__ int meta[192];                                 // 0.75 KB
    const int tid = threadIdx.x;
    const int row0 = blockIdx.x * 64;
    const int wave = tid >> 6, lane = tid & 63;

    // prefetch W1 eighths 0,1: fully hidden under the gather, drained by its barrier
    stage8(W1t, 0, Wsb[0], wave, lane);
    stage8(W1t, 1, Wsb[1], wave, lane);

    const int bstart = (row0 == 0) ? 0 : off[row0 - 1];
    const int cnt = off[row0 + 63] - bstart;
    const bool useLds = (cnt <= IDX_CAP);

    if (tid == 0) sIdx[0] = 0;           // guard for clamped loads when cnt==0
    if (tid < 64) {
        int gr = row0 + tid;
        meta[tid]       = (gr == 0) ? 0 : off[gr - 1];
        meta[64 + tid]  = off[gr];
        meta[128 + tid] = CONV0 ? self_idx[gr] : gr;
    }
    if (useLds)
        for (int i = tid; i < cnt; i += 256) sIdx[i] = items[bstart + i];
    __syncthreads();

    // ---- gather: thread (rb,g) owns rows rb+16i, i=0..3, processed interleaved ----
    const float e = 1.0f + eps_ptr[0];
    const int g = tid & 15;
    const int rb = tid >> 4;        // 0..15
    int st[4], en[4];
    float a[4][8];
#pragma unroll
    for (int i = 0; i < 4; ++i) {
        int r = rb + 16 * i;
        st[i] = meta[r]; en[i] = meta[64 + r];
        int self = meta[128 + r];
        ushort8 u = *(const ushort8*)(tbl + (size_t)self * 128 + g * 8);
#pragma unroll
        for (int j = 0; j < 8; ++j) a[i][j] = e * bf2f(u[j]);
    }
    if (useLds) {
        const int cmax = (cnt > 0) ? (cnt - 1) : 0;
#pragma unroll
        for (int i = 0; i < 4; ++i) { st[i] -= bstart; en[i] -= bstart; }
        while (__ballot((st[0] < en[0]) | (st[1] < en[1]) |
                        (st[2] < en[2]) | (st[3] < en[3]))) {
            ushort8 v[4];
#pragma unroll
            for (int i = 0; i < 4; ++i) {
                int p = st[i] < cmax ? st[i] : cmax;   // clamped: always a valid item
                int idx = sIdx[p];
                v[i] = *(const ushort8*)(tbl + (size_t)idx * 128 + g * 8);
            }
#pragma unroll
            for (int i = 0; i < 4; ++i) {
                if (st[i] < en[i]) {
#pragma unroll
                    for (int j = 0; j < 8; ++j) a[i][j] += bf2f(v[i][j]);
                    st[i]++;
                }
            }
        }
    } else {
#pragma unroll
        for (int i = 0; i < 4; ++i) {
            for (int pos = st[i]; pos < en[i]; ++pos) {
                int rr = items[pos];
                ushort8 v = *(const ushort8*)(tbl + (size_t)rr * 128 + g * 8);
#pragma unroll
                for (int j = 0; j < 8; ++j) a[i][j] += bf2f(v[j]);
            }
        }
    }
#pragma unroll
    for (int i = 0; i < 4; ++i) {
        ushort8 xv;
#pragma unroll
        for (int j = 0; j < 8; ++j) xv[j] = f2bf(a[i][j]);
        *(ushort8*)xs_addr(Xs, g, rb + 16 * i) = xv;
    }
    __syncthreads();   // Xs ready; drains vmcnt(0): gather loads + W1 e0,e1 DMAs

    const int ln = lane & 15, quad = lane >> 4;
    const int row = wave * 16 + ln;   // wave-private X/H row (4 waves x 16 = 64)

    // hoist X fragments (wave reads only its own rows)
    short8 xb[4];
#pragma unroll
    for (int kc = 0; kc < 4; ++kc)
        xb[kc] = *(const short8*)xs_addr(Xs, kc * 4 + quad, row);

    f32x4 acc[8];
#pragma unroll
    for (int t = 0; t < 8; ++t) acc[t] = (f32x4){0.f, 0.f, 0.f, 0.f};

    // ---- GEMM 1 (global steps 0..7): prefetch step+2 (7,8,9 -> W2 e0,e1) ----
#pragma unroll
    for (int s = 0; s < 8; ++s) {
        int pf = s + 2;
        stage8(pf < 8 ? W1t : W2t, pf & 7, Wsb[pf % 3], wave, lane);
        mfma4(Wsb[s % 3], xb, acc[s], quad, ln);
        pipe_barrier<1>();   // retires DMA(s+1); DMA(s+2) stays in flight
    }

    // h = relu(acc + b1) -> Xs (own rows only; same-wave DS ordering suffices)
    {
        const int j0 = (quad & 1) * 4;
#pragma unroll
        for (int t = 0; t < 8; ++t) {
            int p0 = t * 16 + quad * 4;
            f32x4 bv = *(const f32x4*)(b1 + p0);
            u16x4 hp;
#pragma unroll
            for (int i = 0; i < 4; ++i) hp[i] = f2bf(fmaxf(acc[t][i] + bv[i], 0.f));
            *(u16x4*)((char*)xs_addr(Xs, p0 >> 3, row) + j0 * 2) = hp;
        }
    }

    // hoist H fragments (own rows, written by own wave's lanes)
    short8 hb[4];
#pragma unroll
    for (int kc = 0; kc < 4; ++kc)
        hb[kc] = *(const short8*)xs_addr(Xs, kc * 4 + quad, row);

#pragma unroll
    for (int t = 0; t < 8; ++t) acc[t] = (f32x4){0.f, 0.f, 0.f, 0.f};

    // ---- GEMM 2 (global steps 8..15): buffers for steps 8,9 already in flight ----
#pragma unroll
    for (int f = 0; f < 8; ++f) {
        if (f < 6) stage8(W2t, f + 2, Wsb[(f + 10) % 3], wave, lane);
        mfma4(Wsb[(f + 8) % 3], hb, acc[f], quad, ln);
        if (f < 6)      pipe_barrier<1>();
        else if (f == 6) pipe_barrier<0>();   // drain last DMA (step 15) exactly once
    }

    // epilogue: lane holds out[row0+row][n0..n0+3] -> 8B stores
    const int m = row0 + row;
#pragma unroll
    for (int t = 0; t < 8; ++t) {
        int n0 = t * 16 + quad * 4;
        f32x4 bv = *(const f32x4*)(b2 + n0);
        f32x4 gv = *(const f32x4*)(gam + n0);
        f32x4 tv = *(const f32x4*)(bet + n0);
        u16x4 op;
#pragma unroll
        for (int i = 0; i < 4; ++i) {
            float h = acc[t][i] + bv[i];
            h = gv[i] * h * INV_STD + tv[i];
            if (CONV0) h = fmaxf(h, 0.f);
            op[i] = f2bf(h);
        }
        *(u16x4*)(out + (size_t)m * 128 + n0) = op;
    }
}

// ---------------- embedding GEMM (f32 in): out = in @ W + b ----------------
__global__ __launch_bounds__(256) void gemm_embed(
    const float* __restrict__ in, const unsigned short* __restrict__ Wt,
    const float* __restrict__ bias, unsigned short* __restrict__ out_bf, int rows)
{
    __shared__ __align__(16) unsigned short Xs[16 * 64 * 8];
    __shared__ __align__(16) unsigned short Ws[16 * 128 * 8];
    int tid = threadIdx.x;
    int row0 = blockIdx.x * 64;
#pragma unroll
    for (int i = 0; i < 8; ++i) {
        int chunk = tid + i * 256;
        int n = chunk >> 4, g = chunk & 15;
        // source: eighth-linear Wt -> chunk (g, n) at (n>>4)*2048 + g*128 + (n&15)*8
        *(short8*)(Ws + (g * 128 + n) * 8) =
            *(const short8*)(Wt + (n >> 4) * 2048 + g * 128 + (n & 15) * 8);
    }
#pragma unroll
    for (int i = 0; i < 4; ++i) {
        int chunk = tid + i * 256;
        int r = chunk >> 4, g = chunk & 15;
        int gr = row0 + r;
        ushort8 v;
        if (gr < rows) {
            const float* p = in + (size_t)gr * 128 + g * 8;
            f32x4 a0 = *(const f32x4*)p;
            f32x4 a1 = *(const f32x4*)(p + 4);
#pragma unroll
            for (int j = 0; j < 4; ++j) { v[j] = f2bf(a0[j]); v[4 + j] = f2bf(a1[j]); }
        } else {
#pragma unroll
            for (int j = 0; j < 8; ++j) v[j] = 0;
        }
        *(ushort8*)(Xs + (g * 64 + r) * 8) = v;
    }
    __syncthreads();
    int wave = tid >> 6, lane = tid & 63;
    int m0 = wave * 16;
    int ln = lane & 15, quad = lane >> 4;
    f32x4 acc[8];
#pragma unroll
    for (int t = 0; t < 8; ++t) acc[t] = (f32x4){0.f, 0.f, 0.f, 0.f};
#pragma unroll
    for (int kc = 0; kc < 4; ++kc) {
        int g = kc * 4 + quad;
        short8 a = *(const short8*)(Xs + (g * 64 + m0 + ln) * 8);
#pragma unroll
        for (int t = 0; t < 8; ++t) {
            short8 b = *(const short8*)(Ws + (g * 128 + t * 16 + ln) * 8);
            acc[t] = __builtin_amdgcn_mfma_f32_16x16x32_bf16(a, b, acc[t], 0, 0, 0);
        }
    }
#pragma unroll
    for (int t = 0; t < 8; ++t) {
        int col = t * 16 + ln;
        float bi = bias[col];
#pragma unroll
        for (int i = 0; i < 4; ++i) {
            int gr = row0 + m0 + quad * 4 + i;
            if (gr < rows) out_bf[(size_t)gr * 128 + col] = f2bf(acc[t][i] + bi);
        }
    }
}

// ---------------- y projection: y[r][10] (+)= nx[r][:] @ Wp ----------------
template<bool ACCUM>
__global__ __launch_bounds__(256) void proj_y(
    const unsigned short* __restrict__ nx, const float* __restrict__ Wp,
    float* __restrict__ y, int rows)
{
    __shared__ float Wl[HID * NCLS];
    for (int i = threadIdx.x; i < HID * NCLS; i += 256) Wl[i] = Wp[i];
    __syncthreads();
    int r = blockIdx.x * 256 + threadIdx.x;
    if (r >= rows) return;
    float acc[NCLS];
#pragma unroll
    for (int c = 0; c < NCLS; ++c) acc[c] = 0.f;
    const unsigned short* xp = nx + (size_t)r * 128;
#pragma unroll 4
    for (int g = 0; g < 16; ++g) {
        ushort8 u = *(const ushort8*)(xp + g * 8);
#pragma unroll
        for (int j = 0; j < 8; ++j) {
            float xv = bf2f(u[j]);
            const float* w = Wl + (g * 8 + j) * NCLS;
#pragma unroll
            for (int c = 0; c < NCLS; ++c) acc[c] += xv * w[c];
        }
    }
    float* yp = y + (size_t)r * NCLS;
#pragma unroll
    for (int c = 0; c < NCLS; ++c) {
        if (ACCUM) yp[c] += acc[c];
        else yp[c] = acc[c];
    }
}

// ---------------- score scatter: score[b][:] += y[ori[m]][:] ----------------
__global__ __launch_bounds__(256) void score_scatter(
    const float* __restrict__ y, const int* __restrict__ ori,
    const int* __restrict__ batch, float* __restrict__ score)
{
    __shared__ float sc[NBATCH * NCLS];
    for (int i = threadIdx.x; i < NBATCH * NCLS; i += 256) sc[i] = 0.f;
    __syncthreads();
    int stride = gridDim.x * 256;
    for (int m = blockIdx.x * 256 + threadIdx.x; m < M_COPIES; m += stride) {
        int r = ori[m], b = batch[m];
        const float* yp = y + (size_t)r * NCLS;
#pragma unroll
        for (int c = 0; c < NCLS; ++c)
            __hip_atomic_fetch_add(&sc[b * NCLS + c], yp[c],
                                   __ATOMIC_RELAXED, __HIP_MEMORY_SCOPE_WORKGROUP);
    }
    __syncthreads();
    for (int i = threadIdx.x; i < NBATCH * NCLS; i += 256) gatomic_add(score + i, sc[i]);
}

__global__ void score_final(const float* __restrict__ score, const float* __restrict__ bp,
                            float* __restrict__ out)
{
    int t = threadIdx.x;
    if (t >= NBATCH * NCLS) return;
    int c = t % NCLS;
    out[t] = score[t] + bp[c] + bp[NCLS + c] + bp[2 * NCLS + c];
}

__global__ void fill_sentinel(float* out, int n, float enc) {
    int t = blockIdx.x * 64 + threadIdx.x;
    if (t < n) out[t] = enc;
}

// ---------------- entry ----------------
extern "C" void kernel_launch(void* const* d_in, const int* in_sizes, int n_in,
                              void* d_out, int out_size, void* d_ws, size_t ws_size,
                              hipStream_t stream) {
    const float* x_N    = (const float*)d_in[0];
    const float* We     = (const float*)d_in[1];
    const float* be     = (const float*)d_in[2];
    const float* Wg     = (const float*)d_in[3];
    const float* bg     = (const float*)d_in[4];
    const float* eps_g  = (const float*)d_in[5];
    const float* gam    = (const float*)d_in[6];
    const float* bet    = (const float*)d_in[7];
    const float* Wp     = (const float*)d_in[8];
    const float* bp     = (const float*)d_in[9];
    const int* ori_node = (const int*)d_in[10];
    const int* node2edge= (const int*)d_in[11];
    const int* eiN      = (const int*)d_in[12];
    const int* ori_edge = (const int*)d_in[13];
    const int* edge2node= (const int*)d_in[14];
    const int* eiE      = (const int*)d_in[15];
    const int* batch    = (const int*)d_in[16];

    char* p = (char*)d_ws;
    auto take = [&](size_t n) { char* r = p; p += (n + 255) & ~(size_t)255; return r; };
    unsigned short* Wt  = (unsigned short*)take((size_t)17 * 16384 * 2);
    unsigned short* Xb  = (unsigned short*)take((size_t)M_COPIES * 128 * 2);
    unsigned short* Xb2 = (unsigned short*)take((size_t)M_COPIES * 128 * 2);
    unsigned short* nx  = (unsigned short*)take((size_t)N_NODES * 128 * 2);
    unsigned short* ex  = (unsigned short*)take((size_t)N_EDGES * 128 * 2);
    float* y            = (float*)take((size_t)N_NODES * NCLS * 4);
    float* score        = (float*)take((size_t)NBATCH * NCLS * 4);
    int* offN           = (int*)take((size_t)M_COPIES * 4);   // offN/offE contiguous
    int* offE           = (int*)take((size_t)M_COPIES * 4);
    int* off_n2e        = (int*)take((size_t)N_EDGES * 4);
    int* off_e2n        = (int*)take((size_t)N_NODES * 4);
    int* srcsN          = (int*)take((size_t)L_EDGES * 4);
    int* compsN         = (int*)take((size_t)L_EDGES * 4);
    int* srcsE          = (int*)take((size_t)L_EDGES * 4);
    int* compsE         = (int*)take((size_t)L_EDGES * 4);
    int* it_n2e         = (int*)take((size_t)M_COPIES * 4);
    int* it_e2n         = (int*)take((size_t)M_COPIES * 4);
    int* part           = (int*)take((size_t)8192 * 4);
    size_t need = (size_t)(p - (char*)d_ws);
    if (need > ws_size) {
        fill_sentinel<<<(out_size + 63) / 64, 64, 0, stream>>>(
            (float*)d_out, out_size, 1.0e9f + (float)ws_size);
        return;
    }

    prep_w<<<1088, 256, 0, stream>>>(We, Wg, Wt);
    (void)hipMemsetAsync(score, 0, (size_t)NBATCH * NCLS * 4, stream);

    // ---- CSR builds, pairwise fused ----
    const int NB_M = (M_COPIES + 255) / 256;   // 1563
    const int NB_L = (L_EDGES + 255) / 256;    // 3125
    const int NB_N = (N_NODES + 255) / 256;    // 196
    int* partB = part + 4096;

    // edge CSRs (offN from eiN-dst, offE from eiE-dst)
    (void)hipMemsetAsync(offN, 0, (size_t)2 * M_COPIES * 4, stream);  // offN+offE contiguous
    hist2_k<<<NB_L, 256, 0, stream>>>(eiN + L_EDGES, L_EDGES, offN,
                                      eiE + L_EDGES, L_EDGES, offE);
    scan1d_k<<<dim3(NB_M, 2), 256, 0, stream>>>(offN, M_COPIES, part, offE, M_COPIES, partB);
    scan2d_k<<<2, 256, 0, stream>>>(part, NB_M, partB, NB_M);
    scan3d_k<<<dim3(NB_M, 2), 256, 0, stream>>>(offN, M_COPIES, part, offE, M_COPIES, partB);
    fill_edge2_k<<<NB_L, 256, 0, stream>>>(eiN, eiN + L_EDGES, ori_node, L_EDGES, offN, srcsN, compsN,
                                           eiE, eiE + L_EDGES, ori_edge, L_EDGES, offE, srcsE, compsE);

    // pool CSRs (off_n2e over N_EDGES segs, off_e2n over N_NODES segs)
    (void)hipMemsetAsync(off_n2e, 0,
        (size_t)((char*)off_e2n - (char*)off_n2e) + (size_t)N_NODES * 4, stream);
    hist2_k<<<NB_M, 256, 0, stream>>>(node2edge, M_COPIES, off_n2e,
                                      edge2node, M_COPIES, off_e2n);
    scan1d_k<<<dim3(NB_N, 2), 256, 0, stream>>>(off_n2e, N_EDGES, part, off_e2n, N_NODES, partB);
    scan2d_k<<<2, 256, 0, stream>>>(part, (N_EDGES + 255) / 256, partB, NB_N);
    scan3d_k<<<dim3(NB_N, 2), 256, 0, stream>>>(off_n2e, N_EDGES, part, off_e2n, N_NODES, partB);
    fill_pool2_k<<<NB_M, 256, 0, stream>>>(node2edge, M_COPIES, off_n2e, it_n2e,
                                           edge2node, M_COPIES, off_e2n, it_e2n);

    gemm_embed<<<(N_NODES + 63) / 64, 256, 0, stream>>>(x_N, Wt, be, nx, N_NODES);
    proj_y<false><<<(N_NODES + 255) / 256, 256, 0, stream>>>(nx, Wp, y, N_NODES);

    const int MBLK = M_COPIES / 64;   // 6250 blocks of 256 threads
    for (int layer = 0; layer < 2; ++layer) {
        for (int dir = 0; dir < 2; ++dir) {
            int cj0 = layer * 4 + dir * 2;
            int cj1 = cj0 + 1;
            const unsigned short* base = (dir == 0) ? nx : ex;
            const int* selfI = (dir == 0) ? ori_node : ori_edge;
            const int* offD  = (dir == 0) ? offN : offE;
            const int* srcsD = (dir == 0) ? srcsN : srcsE;
            const int* compD = (dir == 0) ? compsN : compsE;

            fused_conv<true><<<MBLK, 256, 0, stream>>>(
                base, selfI, offD, compD, eps_g + cj0,
                Wt + (size_t)(1 + cj0 * 2) * 16384, bg + (cj0 * 2) * 128,
                Wt + (size_t)(1 + cj0 * 2 + 1) * 16384, bg + (cj0 * 2 + 1) * 128,
                gam + cj0 * 128, bet + cj0 * 128, Xb);
            fused_conv<false><<<MBLK, 256, 0, stream>>>(
                Xb, nullptr, offD, srcsD, eps_g + cj1,
                Wt + (size_t)(1 + cj1 * 2) * 16384, bg + (cj1 * 2) * 128,
                Wt + (size_t)(1 + cj1 * 2 + 1) * 16384, bg + (cj1 * 2 + 1) * 128,
                gam + cj1 * 128, bet + cj1 * 128, Xb2);
            if (dir == 0) {
                segsum_pool<<<(N_EDGES + 3) / 4, 256, 0, stream>>>(
                    Xb2, off_n2e, it_n2e, ex, N_EDGES);
            } else {
                segsum_pool<<<(N_NODES + 3) / 4, 256, 0, stream>>>(
                    Xb2, off_e2n, it_e2n, nx, N_NODES);
                proj_y<true><<<(N_NODES + 255) / 256, 256, 0, stream>>>(
                    nx, Wp + (layer + 1) * HID * NCLS, y, N_NODES);
            }
        }
    }
    score_scatter<<<256, 256, 0, stream>>>(y, ori_node, batch, score);
    score_final<<<1, 320, 0, stream>>>(score, bp, (float*)d_out);
}

// Round 5
// 1350.307 us; speedup vs baseline: 1.8404x; 1.0503x over previous
//
#include <hip/hip_runtime.h>
#include <hip/hip_bf16.h>

// ---------------- problem constants ----------------
#define HID 128
static const int N_NODES = 50000;
static const int N_EDGES = 20000;
static const int M_COPIES = 400000;
static const int L_EDGES = 800000;
static const int NBATCH = 32;
static const int NCLS = 10;
#define INV_STD 0.9999950000374997f   // 1/sqrt(1+1e-5)
#define IDX_CAP 384                   // per-chunk item cap (block avg 128)
#define PKSHIFT 19                    // packed entry: (rloc<<19)|val, val<2^19
#define PKMASK  0x7FFFF

typedef __attribute__((ext_vector_type(4))) float f32x4;
typedef __attribute__((ext_vector_type(8))) short short8;      // 8 bf16 lanes
typedef __attribute__((ext_vector_type(8))) unsigned short ushort8;
typedef __attribute__((ext_vector_type(4))) unsigned short u16x4;  // 'ushort4' collides with HIP header

__device__ __forceinline__ float bf2f(unsigned short u) {
    union { unsigned u; float f; } v; v.u = ((unsigned)u) << 16; return v.f;
}
__device__ __forceinline__ unsigned short f2bf(float f) {
    union { float f; unsigned u; } v; v.f = f;
    unsigned r = v.u + 0x7FFFu + ((v.u >> 16) & 1u);   // RNE
    return (unsigned short)(r >> 16);
}
__device__ __forceinline__ void gatomic_add(float* p, float v) {
    unsafeAtomicAdd(p, v);
}

// Swizzled Xs addressing: logical [chunk c][row r][8 bf16], 16 B per (c,r).
// byte = (c*1024 + r*16) ^ ((c&7)<<4) -> gather writes (c fast-varying across
// lanes) land on 8 distinct 16B slots instead of 1 (proven: conflicts 2.88e7->8e5).
__device__ __forceinline__ unsigned short* xs_addr(unsigned short* Xs, int c, int r) {
    int byte = ((c * 64 + r) * 16) ^ ((c & 7) << 4);
    return (unsigned short*)((char*)Xs + byte);
}

// Async DMA of one wave's 1KB quarter of a 4KB W-eighth into LDS (linear copy
// from the eighth-linear Wt image: conflict-free writes, no VGPR round trip).
__device__ __forceinline__ void stage8(const unsigned short* __restrict__ Wmat, int e,
                                       unsigned short* buf, int wave, int lane) {
    const char* g = (const char*)Wmat + ((size_t)e << 12) + (wave << 10) + (lane << 4);
    char* l = (char*)buf + (wave << 10);
    __builtin_amdgcn_global_load_lds(
        (const __attribute__((address_space(1))) unsigned int*)g,
        (__attribute__((address_space(3))) unsigned int*)l,
        16, 0, 0);
}

// Counted-vmcnt barrier (T4): keep DMAs in flight ACROSS the barrier.
// vmem ledger in the GEMM loops is exact: only stage8 DMAs are outstanding
// (gather-phase loads are drained by the gather-end __syncthreads).
template<int N>
__device__ __forceinline__ void pipe_barrier() {
    if constexpr (N == 0) asm volatile("s_waitcnt vmcnt(0)" ::: "memory");
    else                  asm volatile("s_waitcnt vmcnt(1)" ::: "memory");
    __builtin_amdgcn_s_barrier();
    asm volatile("" ::: "memory");
}

// 4 chained MFMAs: one eighth (16 out-channels) x full K for this wave's rows.
__device__ __forceinline__ void mfma4(const unsigned short* Ws, const short8* xv,
                                      f32x4& a, int quad, int ln) {
#pragma unroll
    for (int kc = 0; kc < 4; ++kc) {
        short8 wa = *(const short8*)(Ws + (((kc * 4 + quad) * 16) + ln) * 8);
        a = __builtin_amdgcn_mfma_f32_16x16x32_bf16(wa, xv[kc], a, 0, 0, 0);
    }
}

// ---------------- weight prep: eighth-linear layout ----------------
// Wt[mat] is 8 eighths x 2048 shorts; within an eighth, chunk (gg,n) at
// offset (gg*16+n)*8 holds W[k=gg*8..gg*8+7][col=h*16+n] -> LDS image == global.
__global__ __launch_bounds__(256) void prep_w(const float* __restrict__ We,
                                              const float* __restrict__ Wg,
                                              unsigned short* __restrict__ Wt) {
    int t = blockIdx.x * 256 + threadIdx.x;       // 17*16384
    if (t >= 17 * 16384) return;
    int mat = t >> 14, rem = t & 16383;
    int h = rem >> 11, r2 = rem & 2047;
    int gg = r2 >> 7, r3 = r2 & 127;
    int n = r3 >> 3, j = r3 & 7;
    int k = gg * 8 + j, col = h * 16 + n;
    const float* src = (mat == 0) ? We : (Wg + (size_t)(mat - 1) * 16384);
    Wt[t] = f2bf(src[k * 128 + col]);
}

// ---------------- CSR build ----------------
__global__ __launch_bounds__(256) void hist2_k(
    const int* __restrict__ iA, int nA, int* __restrict__ cA,
    const int* __restrict__ iB, int nB, int* __restrict__ cB, int shift) {
    int t = blockIdx.x * 256 + threadIdx.x;
    if (t < nA) atomicAdd(&cA[iA[t] >> shift], 1);
    if (t < nB) atomicAdd(&cB[iB[t] >> shift], 1);
}

__global__ __launch_bounds__(256) void scan1d_k(
    int* __restrict__ a0, int n0, int* __restrict__ p0,
    int* __restrict__ a1, int n1, int* __restrict__ p1) {
    int* a    = blockIdx.y ? a1 : a0;
    int n     = blockIdx.y ? n1 : n0;
    int* part = blockIdx.y ? p1 : p0;
    if ((int)(blockIdx.x * 256) >= n) return;   // uniform per block
    __shared__ int s[256];
    int i = blockIdx.x * 256 + threadIdx.x;
    int v = (i < n) ? a[i] : 0;
    s[threadIdx.x] = v;
    __syncthreads();
#pragma unroll
    for (int d = 1; d < 256; d <<= 1) {
        int t = (threadIdx.x >= d) ? s[threadIdx.x - d] : 0;
        __syncthreads();
        s[threadIdx.x] += t;
        __syncthreads();
    }
    if (i < n) a[i] = s[threadIdx.x] - v;
    if (threadIdx.x == 255) part[blockIdx.x] = s[255];
}

__global__ __launch_bounds__(256) void scan2d_k(
    int* __restrict__ p0, int nb0, int* __restrict__ p1, int nb1) {
    int* part = blockIdx.x ? p1 : p0;
    int nb    = blockIdx.x ? nb1 : nb0;
    __shared__ int s[256];
    __shared__ int carry;
    if (threadIdx.x == 0) carry = 0;
    __syncthreads();
    for (int base = 0; base < nb; base += 256) {
        int i = base + threadIdx.x;
        int v = (i < nb) ? part[i] : 0;
        s[threadIdx.x] = v;
        __syncthreads();
#pragma unroll
        for (int d = 1; d < 256; d <<= 1) {
            int t = (threadIdx.x >= d) ? s[threadIdx.x - d] : 0;
            __syncthreads();
            s[threadIdx.x] += t;
            __syncthreads();
        }
        if (i < nb) part[i] = carry + s[threadIdx.x] - v;
        __syncthreads();
        if (threadIdx.x == 0) carry += s[255];
        __syncthreads();
    }
}

__global__ __launch_bounds__(256) void scan3d_k(
    int* __restrict__ a0, int n0, const int* __restrict__ p0,
    int* __restrict__ a1, int n1, const int* __restrict__ p1) {
    int* a          = blockIdx.y ? a1 : a0;
    int n           = blockIdx.y ? n1 : n0;
    const int* part = blockIdx.y ? p1 : p0;
    int i = blockIdx.x * 256 + threadIdx.x;
    if (i < n) a[i] += part[blockIdx.x];
}

// Block-granular edge fill: region key = dst>>6 (6250 regions of 64 rows).
// ONE packed int2 store per edge: {.x=(rloc<<19)|src, .y=(rloc<<19)|remap[src]}.
// Writes cluster into ~1KB regions -> far fewer dirty-line touches than the
// old per-row fill (measured 158MB WRITE_SIZE, 12x amplification).
__global__ __launch_bounds__(256) void fill_edgeblk2_k(
    const int* __restrict__ sA, const int* __restrict__ dA, const int* __restrict__ rA,
    int nA, int* __restrict__ oA, int2* __restrict__ pkA,
    const int* __restrict__ sB, const int* __restrict__ dB, const int* __restrict__ rB,
    int nB, int* __restrict__ oB, int2* __restrict__ pkB) {
    int t = blockIdx.x * 256 + threadIdx.x;
    if (t < nA) {
        int d = dA[t]; int pos = atomicAdd(&oA[d >> 6], 1);
        int s = sA[t]; int rl = (d & 63) << PKSHIFT;
        pkA[pos] = (int2){rl | s, rl | rA[s]};
    }
    if (t < nB) {
        int d = dB[t]; int pos = atomicAdd(&oB[d >> 6], 1);
        int s = sB[t]; int rl = (d & 63) << PKSHIFT;
        pkB[pos] = (int2){rl | s, rl | rB[s]};
    }
}

__global__ __launch_bounds__(256) void fill_pool2_k(
    const int* __restrict__ gA, int nA, int* __restrict__ oA, int* __restrict__ itA,
    const int* __restrict__ gB, int nB, int* __restrict__ oB, int* __restrict__ itB) {
    int t = blockIdx.x * 256 + threadIdx.x;
    if (t < nA) { int pos = atomicAdd(&oA[gA[t]], 1); itA[pos] = t; }
    if (t < nB) { int pos = atomicAdd(&oB[gB[t]], 1); itB[pos] = t; }
}

// ---------------- pool segment sum: wave-per-segment, 4 rows in flight ----------------
__global__ __launch_bounds__(256) void segsum_pool(
    const unsigned short* __restrict__ tbl, const int* __restrict__ off,
    const int* __restrict__ items, unsigned short* __restrict__ out, int nseg)
{
    int wave = threadIdx.x >> 6, lane = threadIdx.x & 63;
    int seg = blockIdx.x * 4 + wave;
    if (seg >= nseg) return;
    int start = (seg == 0) ? 0 : off[seg - 1];
    int end = off[seg];
    int g = lane & 15, sub = lane >> 4;
    float a[8] = {0.f, 0.f, 0.f, 0.f, 0.f, 0.f, 0.f, 0.f};
    for (int p = start + sub; p < end; p += 4) {
        int r = items[p];                          // broadcast across the 16 g-lanes
        ushort8 v = *(const ushort8*)(tbl + (size_t)r * 128 + g * 8);
#pragma unroll
        for (int j = 0; j < 8; ++j) a[j] += bf2f(v[j]);
    }
#pragma unroll
    for (int j = 0; j < 8; ++j) {
        a[j] += __shfl_xor(a[j], 16, 64);
        a[j] += __shfl_xor(a[j], 32, 64);
    }
    if (sub == 0) {
        ushort8 ov;
#pragma unroll
        for (int j = 0; j < 8; ++j) ov[j] = f2bf(fmaxf(a[j], 0.f));
        *(ushort8*)(out + (size_t)seg * 128 + g * 8) = ov;
    }
}

// ---------------- fused GIN conv: 256 thr / 64 rows ----------------
// gather-segsum + linear1+ReLU + linear2+BN(+ReLU).
// Block-granular CSR: items for the block's 64 rows arrive unsorted in one
// region; a 64-counter LDS counting sort (hist + wave-0 shuffle prefix +
// scatter) recovers per-row segments, then the proven 4-row-interleaved
// ballot gather runs off sorted LDS. Chunked (IDX_CAP) -> no fallback path.
// W staged via 3x4KB buffers, prefetch depth 2, counted vmcnt(1) (T3/T4).
template<bool CONV0>
__global__ __launch_bounds__(256, 5) void fused_conv(
    const unsigned short* __restrict__ tbl,
    const int* __restrict__ self_idx,
    const int* __restrict__ blkOff, const int2* __restrict__ edgePk,
    const float* __restrict__ eps_ptr,
    const unsigned short* __restrict__ W1t, const float* __restrict__ b1,
    const unsigned short* __restrict__ W2t, const float* __restrict__ b2,
    const float* __restrict__ gam, const float* __restrict__ bet,
    unsigned short* __restrict__ out)
{
    __shared__ __align__(16) unsigned short Xs[16 * 64 * 8];  // 16 KB, swizzled
    __shared__ __align__(16) unsigned short Wsb[3][2048];     // 3 x 4 KB eighth buffers
    __shared__ int sIdx[IDX_CAP];                             // 1.5 KB (sorted values)
    __shared__ int sSelf[64];
    __shared__ int rcnt[64], rbase[64], rpos[64];
    const int tid = threadIdx.x;
    const int row0 = blockIdx.x * 64;
    const int wave = tid >> 6, lane = tid & 63;

    // prefetch W1 eighths 0,1: hidden under the gather, drained by its barriers
    stage8(W1t, 0, Wsb[0], wave, lane);
    stage8(W1t, 1, Wsb[1], wave, lane);

    const int blk = blockIdx.x;
    const int bstart = (blk == 0) ? 0 : blkOff[blk - 1];
    const int cnt = blkOff[blk] - bstart;

    if (tid < 64) sSelf[tid] = CONV0 ? self_idx[row0 + tid] : row0 + tid;
    __syncthreads();

    // ---- self term: thread (rb,g) owns rows rb+16i ----
    const float e = 1.0f + eps_ptr[0];
    const int g = tid & 15;
    const int rb = tid >> 4;        // 0..15
    float a[4][8];
#pragma unroll
    for (int i = 0; i < 4; ++i) {
        int self = sSelf[rb + 16 * i];
        ushort8 u = *(const ushort8*)(tbl + (size_t)self * 128 + g * 8);
#pragma unroll
        for (int j = 0; j < 8; ++j) a[i][j] = e * bf2f(u[j]);
    }

    // ---- chunked: LDS counting sort by row, then interleaved gather ----
    int done = 0;
    while (done < cnt) {
        const int chunk = (cnt - done < IDX_CAP) ? (cnt - done) : IDX_CAP;
        if (tid < 64) rcnt[tid] = 0;
        __syncthreads();
        int e0 = -1, e1 = -1;
        if (tid < chunk) {
            int2 pk = edgePk[bstart + done + tid];
            e0 = CONV0 ? pk.y : pk.x;
            atomicAdd(&rcnt[e0 >> PKSHIFT], 1);
        }
        if (tid + 256 < chunk) {
            int2 pk = edgePk[bstart + done + tid + 256];
            e1 = CONV0 ? pk.y : pk.x;
            atomicAdd(&rcnt[e1 >> PKSHIFT], 1);
        }
        __syncthreads();
        if (tid < 64) {            // wave-0 exclusive prefix over 64 row counts
            int c = rcnt[tid];
            int s = c;
#pragma unroll
            for (int d = 1; d < 64; d <<= 1) {
                int t = __shfl_up(s, d, 64);
                if (tid >= d) s += t;
            }
            rbase[tid] = s - c;
            rpos[tid]  = s - c;
        }
        __syncthreads();
        if (e0 >= 0) { int p = atomicAdd(&rpos[e0 >> PKSHIFT], 1); sIdx[p] = e0 & PKMASK; }
        if (e1 >= 0) { int p = atomicAdd(&rpos[e1 >> PKSHIFT], 1); sIdx[p] = e1 & PKMASK; }
        __syncthreads();           // rpos[r] now == end of row r

        int st[4], en[4];
#pragma unroll
        for (int i = 0; i < 4; ++i) {
            int r = rb + 16 * i;
            st[i] = rbase[r]; en[i] = rpos[r];
        }
        const int cmax = chunk - 1;
        while (__ballot((st[0] < en[0]) | (st[1] < en[1]) |
                        (st[2] < en[2]) | (st[3] < en[3]))) {
            ushort8 v[4];
#pragma unroll
            for (int i = 0; i < 4; ++i) {
                int p = st[i] < cmax ? st[i] : cmax;   // clamped: always valid
                int idx = sIdx[p];
                v[i] = *(const ushort8*)(tbl + (size_t)idx * 128 + g * 8);
            }
#pragma unroll
            for (int i = 0; i < 4; ++i) {
                if (st[i] < en[i]) {
#pragma unroll
                    for (int j = 0; j < 8; ++j) a[i][j] += bf2f(v[i][j]);
                    st[i]++;
                }
            }
        }
        done += chunk;
        __syncthreads();           // protect sIdx/rcnt for next chunk
    }

#pragma unroll
    for (int i = 0; i < 4; ++i) {
        ushort8 xv;
#pragma unroll
        for (int j = 0; j < 8; ++j) xv[j] = f2bf(a[i][j]);
        *(ushort8*)xs_addr(Xs, g, rb + 16 * i) = xv;
    }
    __syncthreads();   // Xs ready; drains vmcnt(0): gather loads + W1 e0,e1 DMAs

    const int ln = lane & 15, quad = lane >> 4;
    const int row = wave * 16 + ln;   // wave-private X/H row (4 waves x 16 = 64)

    // hoist X fragments (wave reads only its own rows)
    short8 xb[4];
#pragma unroll
    for (int kc = 0; kc < 4; ++kc)
        xb[kc] = *(const short8*)xs_addr(Xs, kc * 4 + quad, row);

    f32x4 acc[8];
#pragma unroll
    for (int t = 0; t < 8; ++t) acc[t] = (f32x4){0.f, 0.f, 0.f, 0.f};

    // ---- GEMM 1 (global steps 0..7): prefetch step+2 (7,8,9 -> W2 e0,e1) ----
#pragma unroll
    for (int s = 0; s < 8; ++s) {
        int pf = s + 2;
        stage8(pf < 8 ? W1t : W2t, pf & 7, Wsb[pf % 3], wave, lane);
        mfma4(Wsb[s % 3], xb, acc[s], quad, ln);
        pipe_barrier<1>();   // retires DMA(s+1); DMA(s+2) stays in flight
    }

    // h = relu(acc + b1) -> Xs (own rows only; same-wave DS ordering suffices)
    {
        const int j0 = (quad & 1) * 4;
#pragma unroll
        for (int t = 0; t < 8; ++t) {
            int p0 = t * 16 + quad * 4;
            f32x4 bv = *(const f32x4*)(b1 + p0);
            u16x4 hp;
#pragma unroll
            for (int i = 0; i < 4; ++i) hp[i] = f2bf(fmaxf(acc[t][i] + bv[i], 0.f));
            *(u16x4*)((char*)xs_addr(Xs, p0 >> 3, row) + j0 * 2) = hp;
        }
    }

    // hoist H fragments (own rows, written by own wave's lanes)
    short8 hb[4];
#pragma unroll
    for (int kc = 0; kc < 4; ++kc)
        hb[kc] = *(const short8*)xs_addr(Xs, kc * 4 + quad, row);

#pragma unroll
    for (int t = 0; t < 8; ++t) acc[t] = (f32x4){0.f, 0.f, 0.f, 0.f};

    // ---- GEMM 2 (global steps 8..15): buffers for steps 8,9 already in flight ----
#pragma unroll
    for (int f = 0; f < 8; ++f) {
        if (f < 6) stage8(W2t, f + 2, Wsb[(f + 10) % 3], wave, lane);
        mfma4(Wsb[(f + 8) % 3], hb, acc[f], quad, ln);
        if (f < 6)      pipe_barrier<1>();
        else if (f == 6) pipe_barrier<0>();   // drain last DMA (step 15) exactly once
    }

    // epilogue: lane holds out[row0+row][n0..n0+3] -> 8B stores
    const int m = row0 + row;
#pragma unroll
    for (int t = 0; t < 8; ++t) {
        int n0 = t * 16 + quad * 4;
        f32x4 bv = *(const f32x4*)(b2 + n0);
        f32x4 gv = *(const f32x4*)(gam + n0);
        f32x4 tv = *(const f32x4*)(bet + n0);
        u16x4 op;
#pragma unroll
        for (int i = 0; i < 4; ++i) {
            float h = acc[t][i] + bv[i];
            h = gv[i] * h * INV_STD + tv[i];
            if (CONV0) h = fmaxf(h, 0.f);
            op[i] = f2bf(h);
        }
        *(u16x4*)(out + (size_t)m * 128 + n0) = op;
    }
}

// ---------------- embedding GEMM (f32 in): out = in @ W + b ----------------
__global__ __launch_bounds__(256) void gemm_embed(
    const float* __restrict__ in, const unsigned short* __restrict__ Wt,
    const float* __restrict__ bias, unsigned short* __restrict__ out_bf, int rows)
{
    __shared__ __align__(16) unsigned short Xs[16 * 64 * 8];
    __shared__ __align__(16) unsigned short Ws[16 * 128 * 8];
    int tid = threadIdx.x;
    int row0 = blockIdx.x * 64;
#pragma unroll
    for (int i = 0; i < 8; ++i) {
        int chunk = tid + i * 256;
        int n = chunk >> 4, g = chunk & 15;
        // source: eighth-linear Wt -> chunk (g, n) at (n>>4)*2048 + g*128 + (n&15)*8
        *(short8*)(Ws + (g * 128 + n) * 8) =
            *(const short8*)(Wt + (n >> 4) * 2048 + g * 128 + (n & 15) * 8);
    }
#pragma unroll
    for (int i = 0; i < 4; ++i) {
        int chunk = tid + i * 256;
        int r = chunk >> 4, g = chunk & 15;
        int gr = row0 + r;
        ushort8 v;
        if (gr < rows) {
            const float* p = in + (size_t)gr * 128 + g * 8;
            f32x4 a0 = *(const f32x4*)p;
            f32x4 a1 = *(const f32x4*)(p + 4);
#pragma unroll
            for (int j = 0; j < 4; ++j) { v[j] = f2bf(a0[j]); v[4 + j] = f2bf(a1[j]); }
        } else {
#pragma unroll
            for (int j = 0; j < 8; ++j) v[j] = 0;
        }
        *(ushort8*)(Xs + (g * 64 + r) * 8) = v;
    }
    __syncthreads();
    int wave = tid >> 6, lane = tid & 63;
    int m0 = wave * 16;
    int ln = lane & 15, quad = lane >> 4;
    f32x4 acc[8];
#pragma unroll
    for (int t = 0; t < 8; ++t) acc[t] = (f32x4){0.f, 0.f, 0.f, 0.f};
#pragma unroll
    for (int kc = 0; kc < 4; ++kc) {
        int g = kc * 4 + quad;
        short8 a = *(const short8*)(Xs + (g * 64 + m0 + ln) * 8);
#pragma unroll
        for (int t = 0; t < 8; ++t) {
            short8 b = *(const short8*)(Ws + (g * 128 + t * 16 + ln) * 8);
            acc[t] = __builtin_amdgcn_mfma_f32_16x16x32_bf16(a, b, acc[t], 0, 0, 0);
        }
    }
#pragma unroll
    for (int t = 0; t < 8; ++t) {
        int col = t * 16 + ln;
        float bi = bias[col];
#pragma unroll
        for (int i = 0; i < 4; ++i) {
            int gr = row0 + m0 + quad * 4 + i;
            if (gr < rows) out_bf[(size_t)gr * 128 + col] = f2bf(acc[t][i] + bi);
        }
    }
}

// ---------------- y projection: y[r][10] (+)= nx[r][:] @ Wp ----------------
template<bool ACCUM>
__global__ __launch_bounds__(256) void proj_y(
    const unsigned short* __restrict__ nx, const float* __restrict__ Wp,
    float* __restrict__ y, int rows)
{
    __shared__ float Wl[HID * NCLS];
    for (int i = threadIdx.x; i < HID * NCLS; i += 256) Wl[i] = Wp[i];
    __syncthreads();
    int r = blockIdx.x * 256 + threadIdx.x;
    if (r >= rows) return;
    float acc[NCLS];
#pragma unroll
    for (int c = 0; c < NCLS; ++c) acc[c] = 0.f;
    const unsigned short* xp = nx + (size_t)r * 128;
#pragma unroll 4
    for (int g = 0; g < 16; ++g) {
        ushort8 u = *(const ushort8*)(xp + g * 8);
#pragma unroll
        for (int j = 0; j < 8; ++j) {
            float xv = bf2f(u[j]);
            const float* w = Wl + (g * 8 + j) * NCLS;
#pragma unroll
            for (int c = 0; c < NCLS; ++c) acc[c] += xv * w[c];
        }
    }
    float* yp = y + (size_t)r * NCLS;
#pragma unroll
    for (int c = 0; c < NCLS; ++c) {
        if (ACCUM) yp[c] += acc[c];
        else yp[c] = acc[c];
    }
}

// ---------------- score scatter: score[b][:] += y[ori[m]][:] ----------------
__global__ __launch_bounds__(256) void score_scatter(
    const float* __restrict__ y, const int* __restrict__ ori,
    const int* __restrict__ batch, float* __restrict__ score)
{
    __shared__ float sc[NBATCH * NCLS];
    for (int i = threadIdx.x; i < NBATCH * NCLS; i += 256) sc[i] = 0.f;
    __syncthreads();
    int stride = gridDim.x * 256;
    for (int m = blockIdx.x * 256 + threadIdx.x; m < M_COPIES; m += stride) {
        int r = ori[m], b = batch[m];
        const float* yp = y + (size_t)r * NCLS;
#pragma unroll
        for (int c = 0; c < NCLS; ++c)
            __hip_atomic_fetch_add(&sc[b * NCLS + c], yp[c],
                                   __ATOMIC_RELAXED, __HIP_MEMORY_SCOPE_WORKGROUP);
    }
    __syncthreads();
    for (int i = threadIdx.x; i < NBATCH * NCLS; i += 256) gatomic_add(score + i, sc[i]);
}

__global__ void score_final(const float* __restrict__ score, const float* __restrict__ bp,
                            float* __restrict__ out)
{
    int t = threadIdx.x;
    if (t >= NBATCH * NCLS) return;
    int c = t % NCLS;
    out[t] = score[t] + bp[c] + bp[NCLS + c] + bp[2 * NCLS + c];
}

__global__ void fill_sentinel(float* out, int n, float enc) {
    int t = blockIdx.x * 64 + threadIdx.x;
    if (t < n) out[t] = enc;
}

// ---------------- entry ----------------
extern "C" void kernel_launch(void* const* d_in, const int* in_sizes, int n_in,
                              void* d_out, int out_size, void* d_ws, size_t ws_size,
                              hipStream_t stream) {
    const float* x_N    = (const float*)d_in[0];
    const float* We     = (const float*)d_in[1];
    const float* be     = (const float*)d_in[2];
    const float* Wg     = (const float*)d_in[3];
    const float* bg     = (const float*)d_in[4];
    const float* eps_g  = (const float*)d_in[5];
    const float* gam    = (const float*)d_in[6];
    const float* bet    = (const float*)d_in[7];
    const float* Wp     = (const float*)d_in[8];
    const float* bp     = (const float*)d_in[9];
    const int* ori_node = (const int*)d_in[10];
    const int* node2edge= (const int*)d_in[11];
    const int* eiN      = (const int*)d_in[12];
    const int* ori_edge = (const int*)d_in[13];
    const int* edge2node= (const int*)d_in[14];
    const int* eiE      = (const int*)d_in[15];
    const int* batch    = (const int*)d_in[16];

    const int NBLK = M_COPIES / 64;            // 6250 conv blocks / CSR regions

    char* p = (char*)d_ws;
    auto take = [&](size_t n) { char* r = p; p += (n + 255) & ~(size_t)255; return r; };
    unsigned short* Wt  = (unsigned short*)take((size_t)17 * 16384 * 2);
    unsigned short* Xb  = (unsigned short*)take((size_t)M_COPIES * 128 * 2);
    unsigned short* Xb2 = (unsigned short*)take((size_t)M_COPIES * 128 * 2);
    unsigned short* nx  = (unsigned short*)take((size_t)N_NODES * 128 * 2);
    unsigned short* ex  = (unsigned short*)take((size_t)N_EDGES * 128 * 2);
    float* y            = (float*)take((size_t)N_NODES * NCLS * 4);
    float* score        = (float*)take((size_t)NBATCH * NCLS * 4);
    // blkN/blkE in ONE allocation: NBLK*4 is not 256-aligned, and the memset
    // below must cover both arrays exactly (R4 crash: pad gap left blkE's
    // tail counters unzeroed -> garbage offsets -> OOB pk stores).
    int* blkN           = (int*)take((size_t)2 * NBLK * 4);
    int* blkE           = blkN + NBLK;
    int* off_n2e        = (int*)take((size_t)N_EDGES * 4);    // n2e/e2n contiguous
    int* off_e2n        = (int*)take((size_t)N_NODES * 4);
    int2* pkN           = (int2*)take((size_t)L_EDGES * 8);
    int2* pkE           = (int2*)take((size_t)L_EDGES * 8);
    int* it_n2e         = (int*)take((size_t)M_COPIES * 4);
    int* it_e2n         = (int*)take((size_t)M_COPIES * 4);
    int* part           = (int*)take((size_t)8192 * 4);
    size_t need = (size_t)(p - (char*)d_ws);
    if (need > ws_size) {
        fill_sentinel<<<(out_size + 63) / 64, 64, 0, stream>>>(
            (float*)d_out, out_size, 1.0e9f + (float)ws_size);
        return;
    }

    prep_w<<<1088, 256, 0, stream>>>(We, Wg, Wt);
    (void)hipMemsetAsync(score, 0, (size_t)NBATCH * NCLS * 4, stream);

    // ---- CSR builds ----
    const int NB_M = (M_COPIES + 255) / 256;   // 1563
    const int NB_L = (L_EDGES + 255) / 256;    // 3125
    const int NB_N = (N_NODES + 255) / 256;    // 196
    const int NB_B = (NBLK + 255) / 256;       // 25
    int* partB = part + 4096;

    // edge CSRs at block (64-row) granularity
    (void)hipMemsetAsync(blkN, 0, (size_t)2 * NBLK * 4, stream);   // one contiguous span
    hist2_k<<<NB_L, 256, 0, stream>>>(eiN + L_EDGES, L_EDGES, blkN,
                                      eiE + L_EDGES, L_EDGES, blkE, 6);
    scan1d_k<<<dim3(NB_B, 2), 256, 0, stream>>>(blkN, NBLK, part, blkE, NBLK, partB);
    scan2d_k<<<2, 256, 0, stream>>>(part, NB_B, partB, NB_B);
    scan3d_k<<<dim3(NB_B, 2), 256, 0, stream>>>(blkN, NBLK, part, blkE, NBLK, partB);
    fill_edgeblk2_k<<<NB_L, 256, 0, stream>>>(
        eiN, eiN + L_EDGES, ori_node, L_EDGES, blkN, pkN,
        eiE, eiE + L_EDGES, ori_edge, L_EDGES, blkE, pkE);

    // pool CSRs (off_n2e over N_EDGES segs, off_e2n over N_NODES segs)
    (void)hipMemsetAsync(off_n2e, 0,
        (size_t)((char*)off_e2n - (char*)off_n2e) + (size_t)N_NODES * 4, stream);
    hist2_k<<<NB_M, 256, 0, stream>>>(node2edge, M_COPIES, off_n2e,
                                      edge2node, M_COPIES, off_e2n, 0);
    scan1d_k<<<dim3(NB_N, 2), 256, 0, stream>>>(off_n2e, N_EDGES, part, off_e2n, N_NODES, partB);
    scan2d_k<<<2, 256, 0, stream>>>(part, (N_EDGES + 255) / 256, partB, NB_N);
    scan3d_k<<<dim3(NB_N, 2), 256, 0, stream>>>(off_n2e, N_EDGES, part, off_e2n, N_NODES, partB);
    fill_pool2_k<<<NB_M, 256, 0, stream>>>(node2edge, M_COPIES, off_n2e, it_n2e,
                                           edge2node, M_COPIES, off_e2n, it_e2n);

    gemm_embed<<<(N_NODES + 63) / 64, 256, 0, stream>>>(x_N, Wt, be, nx, N_NODES);
    proj_y<false><<<(N_NODES + 255) / 256, 256, 0, stream>>>(nx, Wp, y, N_NODES);

    for (int layer = 0; layer < 2; ++layer) {
        for (int dir = 0; dir < 2; ++dir) {
            int cj0 = layer * 4 + dir * 2;
            int cj1 = cj0 + 1;
            const unsigned short* base = (dir == 0) ? nx : ex;
            const int* selfI = (dir == 0) ? ori_node : ori_edge;
            const int* blkD  = (dir == 0) ? blkN : blkE;
            const int2* pkD  = (dir == 0) ? pkN : pkE;

            fused_conv<true><<<NBLK, 256, 0, stream>>>(
                base, selfI, blkD, pkD, eps_g + cj0,
                Wt + (size_t)(1 + cj0 * 2) * 16384, bg + (cj0 * 2) * 128,
                Wt + (size_t)(1 + cj0 * 2 + 1) * 16384, bg + (cj0 * 2 + 1) * 128,
                gam + cj0 * 128, bet + cj0 * 128, Xb);
            fused_conv<false><<<NBLK, 256, 0, stream>>>(
                Xb, nullptr, blkD, pkD, eps_g + cj1,
                Wt + (size_t)(1 + cj1 * 2) * 16384, bg + (cj1 * 2) * 128,
                Wt + (size_t)(1 + cj1 * 2 + 1) * 16384, bg + (cj1 * 2 + 1) * 128,
                gam + cj1 * 128, bet + cj1 * 128, Xb2);
            if (dir == 0) {
                segsum_pool<<<(N_EDGES + 3) / 4, 256, 0, stream>>>(
                    Xb2, off_n2e, it_n2e, ex, N_EDGES);
            } else {
                segsum_pool<<<(N_NODES + 3) / 4, 256, 0, stream>>>(
                    Xb2, off_e2n, it_e2n, nx, N_NODES);
                proj_y<true><<<(N_NODES + 255) / 256, 256, 0, stream>>>(
                    nx, Wp + (layer + 1) * HID * NCLS, y, N_NODES);
            }
        }
    }
    score_scatter<<<256, 256, 0, stream>>>(y, ori_node, batch, score);
    score_final<<<1, 320, 0, stream>>>(score, bp, (float*)d_out);
}